// Round 16
// baseline (365.216 us; speedup 1.0000x reference)
//
#include <hip/hip_runtime.h>
#include <hip/hip_bf16.h>
#include <math.h>

typedef __bf16 bf16x8 __attribute__((ext_vector_type(8)));
typedef __bf16 bf16x4 __attribute__((ext_vector_type(4)));
typedef float f32x4 __attribute__((ext_vector_type(4)));

#define MFMA16(a,b,c) __builtin_amdgcn_mfma_f32_16x16x32_bf16(a,b,c,0,0,0)

static constexpr int Nn = 48, Hh = 256;
static constexpr int Ee = 2256, BT = 64;
static constexpr int ETILE = 64, NTILES = 36;          // 36*64 = 2304 >= 2256
static constexpr float BN_RS = 0.9999950000374998f;    // 1/sqrt(1+1e-5)

// ---- ws layout (bytes) ----
static constexpr size_t WS_WF  = 0;         // 4 mats frag-linear + mf1 frags: 557056
static constexpr size_t WS_RRA = 557056;    // 36*2*3*64*8 bf16 = 221184
static constexpr size_t WS_TN  = 778240;    // 268320 f32 = 1073280
static constexpr size_t WS_AGG = 1851520;   // MODE0: g_agg f32 3145728 | MODE1: pm bf16 2359296
static constexpr size_t WS_PB  = 4997248;   // MODE1: bf16 partials 6291456 | MODE0: pm
static constexpr size_t WS_NEED1 = WS_PB + 6291456;  // 11288704

// ---- LDS layout (bytes), total 137728; 1024 threads, 1 block/CU ----
static constexpr int LDS_ACT = 0;        // [64][512B] swizzled act
static constexpr int LDS_ALM = 32768;    // [64][512B] all_msgs act, then h_edges B-frags
static constexpr int LDS_WSG = 65536;    // 2 x 32KB ring of weight chunks (wave-private rows)
static constexpr int LDS_RT  = 131072;   // [64][2] f32
static constexpr int LDS_BS  = 131584;   // 1536 f32 biases
static constexpr int LDS_EDGE_BYTES = 137728;

__device__ __forceinline__ float eluf(float v) { return v > 0.f ? v : __expf(v) - 1.f; }

typedef __attribute__((address_space(1))) const unsigned int as1_uint;
typedef __attribute__((address_space(3))) unsigned int as3_uint;
__device__ __forceinline__ void gload16(const void* g, void* l) {
  __builtin_amdgcn_global_load_lds((as1_uint*)g, (as3_uint*)l, 16, 0, 0);
}

__device__ __forceinline__ int aoff(int e, int colbyte) {
  return e * 512 + (colbyte ^ ((e & 7) << 4));
}

// lgkm-only barrier: LDS writes visible, DMA (vmcnt) stays in flight (T4).
#define LBAR() do { asm volatile("s_waitcnt lgkmcnt(0)" ::: "memory"); \
  __builtin_amdgcn_s_barrier(); __builtin_amdgcn_sched_barrier(0); } while (0)
// per-wave counted DMA wait: all but the 2 newest outstanding vmem ops retired.
#define VWAIT2() do { asm volatile("s_waitcnt vmcnt(2)" ::: "memory"); \
  __builtin_amdgcn_sched_barrier(0); } while (0)

// wave wv stages ONLY its own B rows {wv, wv+16} of a 32KB chunk (wave-private).
__device__ __forceinline__ void issueW(const char* chunkSrc, char* wsgbuf, int wv, int lane) {
  gload16(chunkSrc + wv * 1024 + lane * 16, wsgbuf + wv * 1024);
  gload16(chunkSrc + (16 + wv) * 1024 + lane * 16, wsgbuf + (16 + wv) * 1024);
}

// K=256 GEMM, 16-wave 1Mx16N split, wave-private software-pipelined weight DMA.
// VWAIT2 guarantees chunk c landed (only chunk c+1's 2 loads may stay in flight;
// older stragglers retire first - in-order). NO barriers inside.
__device__ __forceinline__ void gemmK(char* smem, const char* wmat, const char* nextw,
                                      int abase, int lane, int wv, f32x4 acc[4]) {
  char* wsg = smem + LDS_WSG;
  const int kgb = (lane >> 4) * 16;
  const int c16 = lane & 15;
#pragma unroll
  for (int c = 0; c < 4; ++c) {
    VWAIT2();  // chunk c landed (this wave's rows)
#pragma unroll
    for (int ks = 0; ks < 2; ++ks) {
      const int kt = c * 2 + ks;
      bf16x8 bfr = *(const bf16x8*)(wsg + (c & 1) * 32768 + ((ks * 16 + wv) * 64 + lane) * 16);
#pragma unroll
      for (int mt = 0; mt < 4; ++mt) {
        int r = mt * 16 + c16;
        bf16x8 af = *(const bf16x8*)(smem + abase + r * 512 + ((kt * 64 + kgb) ^ ((r & 7) << 4)));
        acc[mt] = MFMA16(af, bfr, acc[mt]);
      }
    }
    __builtin_amdgcn_sched_barrier(0);  // keep re-issue below the ds_reads above
    const char* src = (c < 2) ? (wmat + (c + 2) * 32768) : (nextw + (c - 2) * 32768);
    issueW(src, wsg + (c & 1) * 32768, wv, lane);
  }
}

template<int MODE>
__global__ __launch_bounds__(1024)
void edge_kernel(const float* __restrict__ rel_type,
                 const float* __restrict__ mf2_b, const float* __restrict__ at1_b1,
                 const float* __restrict__ at1_b2, const float* __restrict__ at1_g,
                 const float* __restrict__ at1_be, const __bf16* __restrict__ wf,
                 const __bf16* __restrict__ rra, const __bf16* __restrict__ pmsg,
                 float* __restrict__ g_agg, __bf16* __restrict__ partb) {
  extern __shared__ char smem[];
  float* rt = (float*)(smem + LDS_RT);
  float* bs = (float*)(smem + LDS_BS);
  const char* wfb = (const char*)wf;

  const int tid = threadIdx.x;
  const int lane = tid & 63;
  const int wv = tid >> 6;                // 0..15
  const int lg = lane >> 4;
  const int col16 = lane & 15;
  const int slice = blockIdx.x >> 2;
  const int split = blockIdx.x & 3;
  const int t_begin = split * 9;

  // block-start: bias table (loads+ds_writes resolve before the DMA pipeline starts)
#pragma unroll
  for (int i = 0; i < 2; ++i) {
    int t = i * 1024 + tid;
    if (t < 1536) {
      int which = t >> 8, o = t & 255;
      float v;
      switch (which) {
        case 0: v = mf2_b[o]; break;
        case 1: v = mf2_b[256 + o]; break;
        case 2: v = at1_b1[o]; break;
        case 3: v = at1_b2[o]; break;
        case 4: v = at1_g[o] * BN_RS; break;
        default: v = at1_be[o]; break;
      }
      bs[t] = v;
    }
  }
  // mf1 B-frags: tile-invariant, keep in registers for the whole kernel
  const char* mf1base = wfb + 524288 + ((size_t)(wv * 64 + lane)) * 16;
  bf16x8 wb0 = *(const bf16x8*)(mf1base);
  bf16x8 wb1 = *(const bf16x8*)(mf1base + 16384);
  // fc1 A-operand constants for k-groups 1..3 (bias 1.0 at k=8, zero pad)
  bf16x8 cst = {};
  if (lg == 1) cst[0] = (__bf16)1.0f;

  // start the cross-GEMM DMA pipeline: mf2_0 chunks 0,1 (this wave's rows)
  issueW(wfb, smem + LDS_WSG, wv, lane);
  issueW(wfb + 32768, smem + LDS_WSG + 32768, wv, lane);

  f32x4 ag[3];
#pragma unroll
  for (int a = 0; a < 3; ++a) ag[a] = (f32x4){0.f, 0.f, 0.f, 0.f};
  LBAR();

  for (int tt = 0; tt < 9; ++tt) {
    const int tile = t_begin + tt;
    const int e0 = tile * ETILE;
    const int ne = (Ee - e0 < ETILE) ? (Ee - e0) : ETILE;

    // ---- hoisted per-tile register loads (waits amortize under fc1/gemm) ----
    bf16x8 pmv[4];
    if (lg == 0) {
#pragma unroll
      for (int mt = 0; mt < 4; ++mt)
        pmv[mt] = *(const bf16x8*)(pmsg + ((size_t)slice * 2304 + e0 + mt * 16 + col16) * 8);
    }
    bf16x8 rrv[6];
    {
      const bf16x8* rraw = (const bf16x8*)rra + (size_t)tile * 384;
#pragma unroll
      for (int i = 0; i < 6; ++i) rrv[i] = rraw[i * 64 + lane];
    }
    float rt_ld = 0.f;
    if (tid < ETILE * 2) {
      int e = tid >> 1, i2 = tid & 1;
      rt_ld = (e < ne) ? rel_type[((size_t)slice * Ee + e0 + e) * 2 + i2] : 0.f;
    }
    __builtin_amdgcn_sched_barrier(0);

#pragma unroll 1
    for (int ty = 0; ty < 2; ++ty) {
      {
        // fc1: A = pm (regs, bias folded at k=8), B = mf1 frags (regs)
        const bf16x8 wb = ty ? wb1 : wb0;
        f32x4 fa[4];
#pragma unroll
        for (int mt = 0; mt < 4; ++mt) fa[mt] = (f32x4){0.f, 0.f, 0.f, 0.f};
#pragma unroll
        for (int mt = 0; mt < 4; ++mt) {
          bf16x8 af = (lg == 0) ? pmv[mt] : cst;
          fa[mt] = MFMA16(af, wb, fa[mt]);
        }
        const int cb = (wv * 16 + col16) * 2;
#pragma unroll
        for (int mt = 0; mt < 4; ++mt)
#pragma unroll
          for (int r = 0; r < 4; ++r) {
            int e = mt * 16 + lg * 4 + r;
            *(__bf16*)(smem + LDS_ACT + aoff(e, cb)) = (__bf16)fmaxf(fa[mt][r], 0.f);
          }
      }
      if (ty == 0 && tid < ETILE * 2) rt[tid] = rt_ld;
      LBAR();  // ACT + rt visible to all waves

      f32x4 acc[4];
#pragma unroll
      for (int mt = 0; mt < 4; ++mt) acc[mt] = (f32x4){0.f, 0.f, 0.f, 0.f};
      const char* wm = wfb + (size_t)ty * 131072;
      const char* nx = wfb + (size_t)(ty + 1) * 131072;  // mf2_1 then at1_w1
      gemmK(smem, wm, nx, LDS_ACT, lane, wv, acc);
      const float bbv = bs[ty * 256 + wv * 16 + col16];
      const int cb = (wv * 16 + col16) * 2;
#pragma unroll
      for (int mt = 0; mt < 4; ++mt) {
#pragma unroll
        for (int r = 0; r < 4; ++r) {
          int e = mt * 16 + lg * 4 + r;
          float v = fmaxf(acc[mt][r] + bbv, 0.f) * rt[e * 2 + ty];
          __bf16* p = (__bf16*)(smem + LDS_ALM + aoff(e, cb));
          if (ty == 1) v += (float)*p;  // own patch: same thread wrote it at ty=0
          *p = (__bf16)v;
        }
      }
      LBAR();  // epilogue done: ACT free for next fc1 / ALM visible for at1_l1
    }

    // at1_l1: ALM @ W -> elu -> ACT
    {
      f32x4 acc[4];
#pragma unroll
      for (int mt = 0; mt < 4; ++mt) acc[mt] = (f32x4){0.f, 0.f, 0.f, 0.f};
      gemmK(smem, wfb + (size_t)2 * 131072, wfb + (size_t)3 * 131072, LDS_ALM, lane, wv, acc);
      const float bbv = bs[512 + wv * 16 + col16];
      const int cb = (wv * 16 + col16) * 2;
#pragma unroll
      for (int mt = 0; mt < 4; ++mt)
#pragma unroll
        for (int r = 0; r < 4; ++r) {
          int e = mt * 16 + lg * 4 + r;
          *(__bf16*)(smem + LDS_ACT + aoff(e, cb)) = (__bf16)eluf(acc[mt][r] + bbv);
        }
    }
    LBAR();  // ACT(elu) visible; all waves out of l1-gemm

    // at1_l2: ACT @ W -> elu*sc+be -> h_edges B-frags in ALM
    {
      f32x4 acc[4];
#pragma unroll
      for (int mt = 0; mt < 4; ++mt) acc[mt] = (f32x4){0.f, 0.f, 0.f, 0.f};
      gemmK(smem, wfb + (size_t)3 * 131072, wfb, LDS_ACT, lane, wv, acc);  // next: mf2_0 (next tile)
      const int col = wv * 16 + col16;
      const float b_ = bs[768 + col], s1 = bs[1024 + col], s2 = bs[1280 + col];
      const int j0 = (lg & 1) * 4;
#pragma unroll
      for (int mt = 0; mt < 4; ++mt) {
        const int khalf = mt >> 1;
        const int lane2 = col16 | ((((mt & 1) * 2) + (lg >> 1)) << 4);
        bf16x4 pk;
#pragma unroll
        for (int r = 0; r < 4; ++r)
          pk[r] = (__bf16)(eluf(acc[mt][r] + b_) * s1 + s2);
        int addr = (((khalf * 16 + wv) * 64 + lane2) * 8 + j0) * 2;
        *(bf16x4*)(smem + LDS_ALM + addr) = pk;
      }
    }
    LBAR();  // B-frags visible; all waves out of l2-gemm

    // agg GEMM: ag += rel_rec[tile]^T @ h_edges  (M=48, N=256, K=64); A from rrv regs
#pragma unroll
    for (int kt2 = 0; kt2 < 2; ++kt2) {
      bf16x8 b = *(const bf16x8*)(smem + LDS_ALM + ((kt2 * 16 + wv) * 64 + lane) * 16);
#pragma unroll
      for (int mt2 = 0; mt2 < 3; ++mt2)
        ag[mt2] = MFMA16(rrv[kt2 * 3 + mt2], b, ag[mt2]);
    }
    // fc1 (next tile) writes ACT - disjoint from agg's ALM reads; post-fc1 LBAR gates ALM overwrite
  }

  if (MODE == 1) {
    __bf16* dst = partb + (size_t)blockIdx.x * Nn * Hh;
    const int h = wv * 16 + col16;
#pragma unroll
    for (int mt2 = 0; mt2 < 3; ++mt2)
#pragma unroll
      for (int r = 0; r < 4; ++r) {
        int n = mt2 * 16 + lg * 4 + r;
        dst[n * Hh + h] = (__bf16)ag[mt2][r];
      }
  } else {
    float* dst = g_agg + (size_t)slice * Nn * Hh;
    const int h = wv * 16 + col16;
#pragma unroll
    for (int mt2 = 0; mt2 < 3; ++mt2)
#pragma unroll
      for (int r = 0; r < 4; ++r) {
        int n = mt2 * 16 + lg * 4 + r;
        atomicAdd(dst + n * Hh + h, ag[mt2][r]);
      }
  }
}

// merged prep: [0,128) frag, [128,136) mf1, [136,190) rra, [190,1239) node, [1239,1815) pm
__global__ void prep_all(const float* __restrict__ mf2_w, const float* __restrict__ at1_w1,
                         const float* __restrict__ at1_w2, const float* __restrict__ mf1_w,
                         const float* __restrict__ mf1_b, const float* __restrict__ rel_rec,
                         const float* __restrict__ rel_send, const float* __restrict__ x,
                         const float* __restrict__ at5_w1, const float* __restrict__ at5_w2,
                         const float* __restrict__ o1_w, const float* __restrict__ o2_w,
                         const float* __restrict__ o3_w,
                         __bf16* __restrict__ wfdst, __bf16* __restrict__ rra,
                         __bf16* __restrict__ pmout, float* __restrict__ tn) {
  int b = blockIdx.x;
  if (b < 128) {
    int id = b * 256 + threadIdx.x;  // 32768
    int mat = id >> 13, r = id & 8191;
    int kt = r >> 10, q = r & 1023, nt = q >> 6, l = q & 63;
    int row = nt * 16 + (l & 15), col = kt * 32 + (l >> 4) * 8;
    const float* src = (mat == 0) ? mf2_w : (mat == 1) ? (mf2_w + 65536)
                     : (mat == 2) ? at1_w1 : at1_w2;
    const float* p = src + row * 256 + col;
    __bf16* d = wfdst + (size_t)mat * 65536 + ((size_t)(kt * 16 + nt) * 64 + l) * 8;
#pragma unroll
    for (int j = 0; j < 8; ++j) d[j] = (__bf16)p[j];
    return;
  }
  if (b < 136) {
    int id = (b - 128) * 256 + threadIdx.x;  // 2048
    int ty = id >> 10, q = id & 1023, ntg = q >> 6, l = q & 63;
    int col = ntg * 16 + (l & 15);
    int k0 = (l >> 4) * 8;
    bf16x8 v;
#pragma unroll
    for (int j = 0; j < 8; ++j) {
      int k = k0 + j;
      float xv = (k < 8) ? mf1_w[ty * 2048 + col * 8 + k]
               : (k == 8) ? mf1_b[ty * 256 + col] : 0.f;
      v[j] = (__bf16)xv;
    }
    ((bf16x8*)(wfdst + 262144))[id] = v;
    return;
  }
  if (b < 190) {
    int id = (b - 136) * 256 + threadIdx.x;  // 13824
    if (id >= 13824) return;
    int tile = id / 384, r = id % 384;
    int kt2 = r / 192, r2 = r % 192, mt2 = r2 >> 6, l = r2 & 63;
    int ebase = tile * 64 + kt2 * 32 + (l >> 4) * 8;
    int n = mt2 * 16 + (l & 15);
    bf16x8 v;
#pragma unroll
    for (int j = 0; j < 8; ++j) {
      int e = ebase + j;
      v[j] = (__bf16)((e < Ee) ? rel_rec[(size_t)e * Nn + n] : 0.f);
    }
    ((bf16x8*)rra)[id] = v;
    return;
  }
  if (b < 1239) {
    int id = (b - 190) * 256 + threadIdx.x;
    float* T1 = tn;
    float* T2 = T1 + 67600;
    float* To1 = T2 + 67600;
    float* To2 = To1 + 66560;
    float* To3 = To2 + 65536;
    if (id < 67600) { int o = id % 260, k = id / 260; T1[k * 260 + o] = at5_w1[o * 260 + k]; return; }
    id -= 67600;
    if (id < 67600) { int o = id % 260, k = id / 260; T2[k * 260 + o] = at5_w2[o * 260 + k]; return; }
    id -= 67600;
    if (id < 66560) { int o = id & 255, k = id >> 8; To1[k * 256 + o] = o1_w[o * 260 + k]; return; }
    id -= 66560;
    if (id < 65536) { int o = id & 255, k = id >> 8; To2[k * 256 + o] = o2_w[o * 256 + k]; return; }
    id -= 65536;
    if (id < 1024) { int f = id & 3, k = id >> 2; To3[k * 4 + f] = o3_w[f * 256 + k]; }
    return;
  }
  // pm: pre_msg bf16 [64][2304][8]; senders(f 0..3) then receivers(f 0..3)
  {
    int b2 = b - 1239;                 // 576 blocks
    int slice = b2 / 9, ec = b2 % 9;
    __shared__ float xsl[192];
    if (threadIdx.x < 192) xsl[threadIdx.x] = x[slice * 192 + threadIdx.x];
    __syncthreads();
    int e = ec * 256 + threadIdx.x;    // < 2304
    bf16x8 v = {};
    if (e < Ee) {
      const float* rs = rel_send + (size_t)e * Nn;
      const float* rr = rel_rec + (size_t)e * Nn;
      float a[8] = {0.f, 0.f, 0.f, 0.f, 0.f, 0.f, 0.f, 0.f};
      for (int n = 0; n < Nn; ++n) {
        float sv = rs[n], rv = rr[n];
#pragma unroll
        for (int f = 0; f < 4; ++f) {
          a[f] = fmaf(sv, xsl[n * 4 + f], a[f]);
          a[4 + f] = fmaf(rv, xsl[n * 4 + f], a[4 + f]);
        }
      }
#pragma unroll
      for (int j = 0; j < 8; ++j) v[j] = (__bf16)a[j];
    }
    ((bf16x8*)pmout)[(size_t)slice * 2304 + e] = v;
  }
}

// 512 blocks x 6 node-rows each; LDS reads quad-vectorized (b128)
template<int MODE>
__global__ __launch_bounds__(256, 4)
void node_kernel(const float* __restrict__ g_agg, const __bf16* __restrict__ partb,
                 const float* __restrict__ x,
                 const float* __restrict__ T1, const float* __restrict__ T2,
                 const float* __restrict__ To1, const float* __restrict__ To2,
                 const float* __restrict__ To3, const float* __restrict__ at5_b1,
                 const float* __restrict__ at5_b2, const float* __restrict__ at5_g,
                 const float* __restrict__ at5_be, const float* __restrict__ o1_b,
                 const float* __restrict__ o2_b, const float* __restrict__ o3_b,
                 float* __restrict__ out) {
  __shared__ __align__(16) float bufA[6 * 264], bufB[6 * 264];
  __shared__ float xres[6 * 4];
  const int tid = threadIdx.x;
  const int slice = blockIdx.x >> 3, rg = blockIdx.x & 7;
  const int n0 = rg * 6;
  for (int t = tid; t < 6 * 256; t += 256) {
    int r = t >> 8, h = t & 255;
    float s;
    if (MODE == 1) {
      s = 0.f;
#pragma unroll
      for (int sp = 0; sp < 4; ++sp)
        s += (float)partb[((((size_t)slice * 4 + sp) * Nn) + n0 + r) * Hh + h];
    } else {
      s = g_agg[(size_t)slice * 12288 + (size_t)(n0 + r) * 256 + h];
    }
    bufA[r * 264 + h] = s;
  }
  if (tid < 24) {
    int r = tid >> 2, f = tid & 3;
    float v = x[(size_t)slice * 192 + (n0 + r) * 4 + f];
    bufA[r * 264 + 256 + f] = v;
    xres[tid] = v;
  }
  __syncthreads();

  auto layer = [&](const float* WT, const float* bsrc, const float* in, float* outb,
                   int K, int O, int act, const float* gsc, const float* gbe) {
    for (int o = tid; o < O; o += 256) {
      float a[6];
      float bb = bsrc[o];
#pragma unroll
      for (int r = 0; r < 6; ++r) a[r] = bb;
      for (int k = 0; k < K; k += 4) {
        float w0 = WT[k * O + o], w1 = WT[(k + 1) * O + o];
        float w2 = WT[(k + 2) * O + o], w3 = WT[(k + 3) * O + o];
#pragma unroll
        for (int r = 0; r < 6; ++r) {
          f32x4 iv = *(const f32x4*)(in + r * 264 + k);
          a[r] = fmaf(iv[0], w0, a[r]);
          a[r] = fmaf(iv[1], w1, a[r]);
          a[r] = fmaf(iv[2], w2, a[r]);
          a[r] = fmaf(iv[3], w3, a[r]);
        }
      }
      float scv = 1.f, bev = 0.f;
      if (act == 2) { scv = gsc[o] * BN_RS; bev = gbe[o]; }
#pragma unroll
      for (int r = 0; r < 6; ++r) {
        float v = a[r];
        v = (act == 0) ? fmaxf(v, 0.f) : eluf(v);
        if (act == 2) v = v * scv + bev;
        outb[r * 264 + o] = v;
      }
    }
    __syncthreads();
  };

  layer(T1, at5_b1, bufA, bufB, 260, 260, 1, nullptr, nullptr);
  layer(T2, at5_b2, bufB, bufA, 260, 260, 2, at5_g, at5_be);
  layer(To1, o1_b, bufA, bufB, 260, 256, 0, nullptr, nullptr);
  layer(To2, o2_b, bufB, bufA, 256, 256, 0, nullptr, nullptr);
  if (tid < 24) {
    int r = tid >> 2, f = tid & 3;
    float s = o3_b[f];
    for (int k = 0; k < 256; k += 4) {
      f32x4 iv = *(const f32x4*)(bufA + r * 264 + k);
      s = fmaf(iv[0], To3[k * 4 + f], s);
      s = fmaf(iv[1], To3[(k + 1) * 4 + f], s);
      s = fmaf(iv[2], To3[(k + 2) * 4 + f], s);
      s = fmaf(iv[3], To3[(k + 3) * 4 + f], s);
    }
    out[(size_t)slice * 192 + (n0 + r) * 4 + f] = xres[tid] + s;
  }
}

extern "C" void kernel_launch(void* const* d_in, const int* in_sizes, int n_in,
                              void* d_out, int out_size, void* d_ws, size_t ws_size,
                              hipStream_t stream) {
  const float* x = (const float*)d_in[0];
  const float* rel_rec = (const float*)d_in[1];
  const float* rel_send = (const float*)d_in[2];
  const float* rel_type = (const float*)d_in[3];
  const float* mf1_w = (const float*)d_in[4];
  const float* mf1_b = (const float*)d_in[5];
  const float* mf2_w = (const float*)d_in[6];
  const float* mf2_b = (const float*)d_in[7];
  const float* at1_w1 = (const float*)d_in[8];
  const float* at1_b1 = (const float*)d_in[9];
  const float* at1_w2 = (const float*)d_in[10];
  const float* at1_b2 = (const float*)d_in[11];
  const float* at1_g = (const float*)d_in[12];
  const float* at1_be = (const float*)d_in[13];
  const float* at5_w1 = (const float*)d_in[14];
  const float* at5_b1 = (const float*)d_in[15];
  const float* at5_w2 = (const float*)d_in[16];
  const float* at5_b2 = (const float*)d_in[17];
  const float* at5_g = (const float*)d_in[18];
  const float* at5_be = (const float*)d_in[19];
  const float* o1_w = (const float*)d_in[20];
  const float* o1_b = (const float*)d_in[21];
  const float* o2_w = (const float*)d_in[22];
  const float* o2_b = (const float*)d_in[23];
  const float* o3_w = (const float*)d_in[24];
  const float* o3_b = (const float*)d_in[25];

  char* ws = (char*)d_ws;
  __bf16* wf = (__bf16*)(ws + WS_WF);
  __bf16* rra = (__bf16*)(ws + WS_RRA);
  float* tnode = (float*)(ws + WS_TN);
  float* g_agg = (float*)(ws + WS_AGG);
  __bf16* partb = (__bf16*)(ws + WS_PB);

  const int mode = (ws_size >= WS_NEED1) ? 1 : 0;
  // MODE1: pm lives in the (unused) g_agg slot; MODE0: pm at WS_PB (partb unused)
  __bf16* pm = (mode == 1) ? (__bf16*)(ws + WS_AGG) : (__bf16*)(ws + WS_PB);

  prep_all<<<1815, 256, 0, stream>>>(mf2_w, at1_w1, at1_w2, mf1_w, mf1_b, rel_rec,
                                     rel_send, x, at5_w1, at5_w2, o1_w, o2_w, o3_w,
                                     wf, rra, pm, tnode);

  if (mode == 1) {
    hipFuncSetAttribute((const void*)edge_kernel<1>,
                        hipFuncAttributeMaxDynamicSharedMemorySize, LDS_EDGE_BYTES);
    edge_kernel<1><<<BT * 4, 1024, LDS_EDGE_BYTES, stream>>>(
        rel_type, mf2_b, at1_b1, at1_b2, at1_g, at1_be, wf, rra, pm, g_agg, partb);
    node_kernel<1><<<512, 256, 0, stream>>>(g_agg, partb, x, tnode, tnode + 67600,
                                            tnode + 135200, tnode + 201760, tnode + 267296,
                                            at5_b1, at5_b2, at5_g, at5_be,
                                            o1_b, o2_b, o3_b, (float*)d_out);
  } else {
    hipMemsetAsync(g_agg, 0, (size_t)BT * Nn * Hh * 4, stream);
    hipFuncSetAttribute((const void*)edge_kernel<0>,
                        hipFuncAttributeMaxDynamicSharedMemorySize, LDS_EDGE_BYTES);
    edge_kernel<0><<<BT * 4, 1024, LDS_EDGE_BYTES, stream>>>(
        rel_type, mf2_b, at1_b1, at1_b2, at1_g, at1_be, wf, rra, pm, g_agg, partb);
    node_kernel<0><<<512, 256, 0, stream>>>(g_agg, partb, x, tnode, tnode + 67600,
                                            tnode + 135200, tnode + 201760, tnode + 267296,
                                            at5_b1, at5_b2, at5_g, at5_be,
                                            o1_b, o2_b, o3_b, (float*)d_out);
  }
}

// Round 17
// 276.991 us; speedup vs baseline: 1.3185x; 1.3185x over previous
//
#include <hip/hip_runtime.h>
#include <hip/hip_bf16.h>
#include <math.h>

typedef __bf16 bf16x8 __attribute__((ext_vector_type(8)));
typedef __bf16 bf16x4 __attribute__((ext_vector_type(4)));
typedef float f32x4 __attribute__((ext_vector_type(4)));

#define MFMA16(a,b,c) __builtin_amdgcn_mfma_f32_16x16x32_bf16(a,b,c,0,0,0)

static constexpr int Nn = 48, Hh = 256;
static constexpr int Ee = 2256, BT = 64;
static constexpr int ETILE = 64, NTILES = 36;          // 36*64 = 2304 >= 2256
static constexpr float BN_RS = 0.9999950000374998f;    // 1/sqrt(1+1e-5)

// ---- ws layout (bytes) ----
static constexpr size_t WS_WF  = 0;         // 4 mats frag-linear + mf1 frags: 557056
static constexpr size_t WS_RRA = 557056;    // 36*2*3*64*8 bf16 = 221184
static constexpr size_t WS_TN  = 778240;    // 268320 f32 = 1073280
static constexpr size_t WS_AGG = 1851520;   // MODE0: g_agg f32 3145728 | MODE1: pm bf16 2359296
static constexpr size_t WS_PB  = 4997248;   // MODE1: bf16 partials 6291456 | MODE0: pm
static constexpr size_t WS_NEED1 = WS_PB + 6291456;  // 11288704

// ---- LDS layout (bytes), total 137728; 1024 threads, 1 block/CU ----
static constexpr int LDS_ACT = 0;        // [64][512B] swizzled act
static constexpr int LDS_ALM = 32768;    // [64][512B] all_msgs act, then h_edges B-frags
static constexpr int LDS_WSG = 65536;    // 2 x 32KB ring of weight chunks (wave-private rows)
static constexpr int LDS_RT  = 131072;   // [64][2] f32
static constexpr int LDS_BS  = 131584;   // 1536 f32 biases
static constexpr int LDS_EDGE_BYTES = 137728;

__device__ __forceinline__ float eluf(float v) { return v > 0.f ? v : __expf(v) - 1.f; }

typedef __attribute__((address_space(1))) const unsigned int as1_uint;
typedef __attribute__((address_space(3))) unsigned int as3_uint;
__device__ __forceinline__ void gload16(const void* g, void* l) {
  __builtin_amdgcn_global_load_lds((as1_uint*)g, (as3_uint*)l, 16, 0, 0);
}

__device__ __forceinline__ int aoff(int e, int colbyte) {
  return e * 512 + (colbyte ^ ((e & 7) << 4));
}

// lgkm-only barrier: LDS writes visible, DMA (vmcnt) stays in flight (T4).
#define LBAR() do { asm volatile("s_waitcnt lgkmcnt(0)" ::: "memory"); \
  __builtin_amdgcn_s_barrier(); __builtin_amdgcn_sched_barrier(0); } while (0)
// per-wave counted DMA wait: all but the 2 newest outstanding vmem ops retired.
#define VWAIT2() do { asm volatile("s_waitcnt vmcnt(2)" ::: "memory"); \
  __builtin_amdgcn_sched_barrier(0); } while (0)

// wave wv stages ONLY its own B rows {wv, wv+16} of a 32KB chunk (wave-private).
__device__ __forceinline__ void issueW(const char* chunkSrc, char* wsgbuf, int wv, int lane) {
  gload16(chunkSrc + wv * 1024 + lane * 16, wsgbuf + wv * 1024);
  gload16(chunkSrc + (16 + wv) * 1024 + lane * 16, wsgbuf + (16 + wv) * 1024);
}

// K=256 GEMM, 16-wave 1Mx16N split, wave-private software-pipelined weight DMA.
// Invariant: this wave's chunks 0,1 of wmat already issued (in order), newest
// outstanding. Iterations 2,3 pre-issue nextw's chunks 0,1. NO barriers inside.
__device__ __forceinline__ void gemmK(char* smem, const char* wmat, const char* nextw,
                                      int abase, int lane, int wv, f32x4 acc[4]) {
  char* wsg = smem + LDS_WSG;
  const int kgb = (lane >> 4) * 16;
  const int c16 = lane & 15;
#pragma unroll
  for (int c = 0; c < 4; ++c) {
    VWAIT2();  // chunk c landed (this wave's rows)
#pragma unroll
    for (int ks = 0; ks < 2; ++ks) {
      const int kt = c * 2 + ks;
      bf16x8 bfr = *(const bf16x8*)(wsg + (c & 1) * 32768 + ((ks * 16 + wv) * 64 + lane) * 16);
#pragma unroll
      for (int mt = 0; mt < 4; ++mt) {
        int r = mt * 16 + c16;
        bf16x8 af = *(const bf16x8*)(smem + abase + r * 512 + ((kt * 64 + kgb) ^ ((r & 7) << 4)));
        acc[mt] = MFMA16(af, bfr, acc[mt]);
      }
    }
    __builtin_amdgcn_sched_barrier(0);  // keep re-issue below the ds_reads above
    const char* src = (c < 2) ? (wmat + (c + 2) * 32768) : (nextw + (c - 2) * 32768);
    issueW(src, wsg + (c & 1) * 32768, wv, lane);
  }
}

template<int MODE>
__global__ __launch_bounds__(1024)
void edge_kernel(const float* __restrict__ rel_type,
                 const float* __restrict__ mf2_b, const float* __restrict__ at1_b1,
                 const float* __restrict__ at1_b2, const float* __restrict__ at1_g,
                 const float* __restrict__ at1_be, const __bf16* __restrict__ wf,
                 const __bf16* __restrict__ rra, const __bf16* __restrict__ pmsg,
                 float* __restrict__ g_agg, __bf16* __restrict__ partb) {
  extern __shared__ char smem[];
  float* rt = (float*)(smem + LDS_RT);
  float* bs = (float*)(smem + LDS_BS);
  const char* wfb = (const char*)wf;

  const int tid = threadIdx.x;
  const int lane = tid & 63;
  const int wv = tid >> 6;                // 0..15
  const int lg = lane >> 4;
  const int col16 = lane & 15;
  const int slice = blockIdx.x >> 2;
  const int split = blockIdx.x & 3;
  const int t_begin = split * 9;

  // block-start: bias table (resolves before the DMA pipeline starts)
#pragma unroll
  for (int i = 0; i < 2; ++i) {
    int t = i * 1024 + tid;
    if (t < 1536) {
      int which = t >> 8, o = t & 255;
      float v;
      switch (which) {
        case 0: v = mf2_b[o]; break;
        case 1: v = mf2_b[256 + o]; break;
        case 2: v = at1_b1[o]; break;
        case 3: v = at1_b2[o]; break;
        case 4: v = at1_g[o] * BN_RS; break;
        default: v = at1_be[o]; break;
      }
      bs[t] = v;
    }
  }
  // fc1 A-operand constant for k-groups 1..3 (bias 1.0 at k=8, zero pad)
  bf16x8 cst = {};
  if (lg == 1) cst[0] = (__bf16)1.0f;

  // start the cross-GEMM DMA pipeline: mf2_0 chunks 0,1 (this wave's rows)
  issueW(wfb, smem + LDS_WSG, wv, lane);
  issueW(wfb + 32768, smem + LDS_WSG + 32768, wv, lane);

  f32x4 ag[3];
#pragma unroll
  for (int a = 0; a < 3; ++a) ag[a] = (f32x4){0.f, 0.f, 0.f, 0.f};
  LBAR();

  for (int tt = 0; tt < 9; ++tt) {
    const int tile = t_begin + tt;
    const int e0 = tile * ETILE;
    const int ne = (Ee - e0 < ETILE) ? (Ee - e0) : ETILE;

    // rt -> LDS (visible at the post-fc1 LBAR; epilogue reads it after that)
    if (tid < ETILE * 2) {
      int e = tid >> 1, i2 = tid & 1;
      rt[tid] = (e < ne) ? rel_type[((size_t)slice * Ee + e0 + e) * 2 + i2] : 0.f;
    }

#pragma unroll 1
    for (int ty = 0; ty < 2; ++ty) {
      {
        // fc1: A = pm (regs, bias folded at k=8), B = mf1 frags (per-ty load).
        // pmv/wb live only inside this scope (64-VGPR budget; r16's hoist spilled).
        bf16x8 pmv[4];
        if (lg == 0) {
#pragma unroll
          for (int mt = 0; mt < 4; ++mt)
            pmv[mt] = *(const bf16x8*)(pmsg + ((size_t)slice * 2304 + e0 + mt * 16 + col16) * 8);
        }
        bf16x8 wb = *(const bf16x8*)(wfb + 524288 + ty * 16384 +
                                     ((size_t)(wv * 64 + lane)) * 16);
        f32x4 fa[4];
#pragma unroll
        for (int mt = 0; mt < 4; ++mt) fa[mt] = (f32x4){0.f, 0.f, 0.f, 0.f};
#pragma unroll
        for (int mt = 0; mt < 4; ++mt) {
          bf16x8 af = (lg == 0) ? pmv[mt] : cst;
          fa[mt] = MFMA16(af, wb, fa[mt]);
        }
        const int cb = (wv * 16 + col16) * 2;
#pragma unroll
        for (int mt = 0; mt < 4; ++mt)
#pragma unroll
          for (int r = 0; r < 4; ++r) {
            int e = mt * 16 + lg * 4 + r;
            *(__bf16*)(smem + LDS_ACT + aoff(e, cb)) = (__bf16)fmaxf(fa[mt][r], 0.f);
          }
      }
      LBAR();  // ACT + rt visible to all waves

      f32x4 acc[4];
#pragma unroll
      for (int mt = 0; mt < 4; ++mt) acc[mt] = (f32x4){0.f, 0.f, 0.f, 0.f};
      const char* wm = wfb + (size_t)ty * 131072;
      const char* nx = wfb + (size_t)(ty + 1) * 131072;  // mf2_1 then at1_w1
      gemmK(smem, wm, nx, LDS_ACT, lane, wv, acc);
      const float bbv = bs[ty * 256 + wv * 16 + col16];
      const int cb = (wv * 16 + col16) * 2;
#pragma unroll
      for (int mt = 0; mt < 4; ++mt) {
#pragma unroll
        for (int r = 0; r < 4; ++r) {
          int e = mt * 16 + lg * 4 + r;
          float v = fmaxf(acc[mt][r] + bbv, 0.f) * rt[e * 2 + ty];
          __bf16* p = (__bf16*)(smem + LDS_ALM + aoff(e, cb));
          if (ty == 1) v += (float)*p;  // own patch: same thread wrote it at ty=0
          *p = (__bf16)v;
        }
      }
      LBAR();  // epilogue done: ACT free for next fc1 / ALM visible for at1_l1
    }

    // at1_l1: ALM @ W -> elu -> ACT
    {
      f32x4 acc[4];
#pragma unroll
      for (int mt = 0; mt < 4; ++mt) acc[mt] = (f32x4){0.f, 0.f, 0.f, 0.f};
      gemmK(smem, wfb + (size_t)2 * 131072, wfb + (size_t)3 * 131072, LDS_ALM, lane, wv, acc);
      const float bbv = bs[512 + wv * 16 + col16];
      const int cb = (wv * 16 + col16) * 2;
#pragma unroll
      for (int mt = 0; mt < 4; ++mt)
#pragma unroll
        for (int r = 0; r < 4; ++r) {
          int e = mt * 16 + lg * 4 + r;
          *(__bf16*)(smem + LDS_ACT + aoff(e, cb)) = (__bf16)eluf(acc[mt][r] + bbv);
        }
    }
    LBAR();  // ACT(elu) visible; all waves out of l1-gemm

    // at1_l2: ACT @ W -> elu*sc+be -> h_edges B-frags in ALM
    {
      f32x4 acc[4];
#pragma unroll
      for (int mt = 0; mt < 4; ++mt) acc[mt] = (f32x4){0.f, 0.f, 0.f, 0.f};
      gemmK(smem, wfb + (size_t)3 * 131072, wfb, LDS_ACT, lane, wv, acc);  // next: mf2_0 (next tile)
      const int col = wv * 16 + col16;
      const float b_ = bs[768 + col], s1 = bs[1024 + col], s2 = bs[1280 + col];
      const int j0 = (lg & 1) * 4;
#pragma unroll
      for (int mt = 0; mt < 4; ++mt) {
        const int khalf = mt >> 1;
        const int lane2 = col16 | ((((mt & 1) * 2) + (lg >> 1)) << 4);
        bf16x4 pk;
#pragma unroll
        for (int r = 0; r < 4; ++r)
          pk[r] = (__bf16)(eluf(acc[mt][r] + b_) * s1 + s2);
        int addr = (((khalf * 16 + wv) * 64 + lane2) * 8 + j0) * 2;
        *(bf16x4*)(smem + LDS_ALM + addr) = pk;
      }
    }
    LBAR();  // B-frags visible; all waves out of l2-gemm

    // agg GEMM: ag += rel_rec[tile]^T @ h_edges  (M=48, N=256, K=64)
    const bf16x8* rraw = (const bf16x8*)rra + (size_t)tile * 384;
#pragma unroll
    for (int kt2 = 0; kt2 < 2; ++kt2) {
      bf16x8 b = *(const bf16x8*)(smem + LDS_ALM + ((kt2 * 16 + wv) * 64 + lane) * 16);
#pragma unroll
      for (int mt2 = 0; mt2 < 3; ++mt2) {
        bf16x8 a = rraw[(kt2 * 3 + mt2) * 64 + lane];
        ag[mt2] = MFMA16(a, b, ag[mt2]);
      }
    }
    // next tile's fc1 writes ACT (disjoint); post-fc1 LBAR gates ALM overwrite
  }

  if (MODE == 1) {
    __bf16* dst = partb + (size_t)blockIdx.x * Nn * Hh;
    const int h = wv * 16 + col16;
#pragma unroll
    for (int mt2 = 0; mt2 < 3; ++mt2)
#pragma unroll
      for (int r = 0; r < 4; ++r) {
        int n = mt2 * 16 + lg * 4 + r;
        dst[n * Hh + h] = (__bf16)ag[mt2][r];
      }
  } else {
    float* dst = g_agg + (size_t)slice * Nn * Hh;
    const int h = wv * 16 + col16;
#pragma unroll
    for (int mt2 = 0; mt2 < 3; ++mt2)
#pragma unroll
      for (int r = 0; r < 4; ++r) {
        int n = mt2 * 16 + lg * 4 + r;
        atomicAdd(dst + n * Hh + h, ag[mt2][r]);
      }
  }
}

// merged prep: [0,128) frag, [128,136) mf1, [136,190) rra, [190,1239) node, [1239,1815) pm
__global__ void prep_all(const float* __restrict__ mf2_w, const float* __restrict__ at1_w1,
                         const float* __restrict__ at1_w2, const float* __restrict__ mf1_w,
                         const float* __restrict__ mf1_b, const float* __restrict__ rel_rec,
                         const float* __restrict__ rel_send, const float* __restrict__ x,
                         const float* __restrict__ at5_w1, const float* __restrict__ at5_w2,
                         const float* __restrict__ o1_w, const float* __restrict__ o2_w,
                         const float* __restrict__ o3_w,
                         __bf16* __restrict__ wfdst, __bf16* __restrict__ rra,
                         __bf16* __restrict__ pmout, float* __restrict__ tn) {
  int b = blockIdx.x;
  if (b < 128) {
    int id = b * 256 + threadIdx.x;  // 32768
    int mat = id >> 13, r = id & 8191;
    int kt = r >> 10, q = r & 1023, nt = q >> 6, l = q & 63;
    int row = nt * 16 + (l & 15), col = kt * 32 + (l >> 4) * 8;
    const float* src = (mat == 0) ? mf2_w : (mat == 1) ? (mf2_w + 65536)
                     : (mat == 2) ? at1_w1 : at1_w2;
    const float* p = src + row * 256 + col;
    __bf16* d = wfdst + (size_t)mat * 65536 + ((size_t)(kt * 16 + nt) * 64 + l) * 8;
#pragma unroll
    for (int j = 0; j < 8; ++j) d[j] = (__bf16)p[j];
    return;
  }
  if (b < 136) {
    int id = (b - 128) * 256 + threadIdx.x;  // 2048
    int ty = id >> 10, q = id & 1023, ntg = q >> 6, l = q & 63;
    int col = ntg * 16 + (l & 15);
    int k0 = (l >> 4) * 8;
    bf16x8 v;
#pragma unroll
    for (int j = 0; j < 8; ++j) {
      int k = k0 + j;
      float xv = (k < 8) ? mf1_w[ty * 2048 + col * 8 + k]
               : (k == 8) ? mf1_b[ty * 256 + col] : 0.f;
      v[j] = (__bf16)xv;
    }
    ((bf16x8*)(wfdst + 262144))[id] = v;
    return;
  }
  if (b < 190) {
    int id = (b - 136) * 256 + threadIdx.x;  // 13824
    if (id >= 13824) return;
    int tile = id / 384, r = id % 384;
    int kt2 = r / 192, r2 = r % 192, mt2 = r2 >> 6, l = r2 & 63;
    int ebase = tile * 64 + kt2 * 32 + (l >> 4) * 8;
    int n = mt2 * 16 + (l & 15);
    bf16x8 v;
#pragma unroll
    for (int j = 0; j < 8; ++j) {
      int e = ebase + j;
      v[j] = (__bf16)((e < Ee) ? rel_rec[(size_t)e * Nn + n] : 0.f);
    }
    ((bf16x8*)rra)[id] = v;
    return;
  }
  if (b < 1239) {
    int id = (b - 190) * 256 + threadIdx.x;
    float* T1 = tn;
    float* T2 = T1 + 67600;
    float* To1 = T2 + 67600;
    float* To2 = To1 + 66560;
    float* To3 = To2 + 65536;
    if (id < 67600) { int o = id % 260, k = id / 260; T1[k * 260 + o] = at5_w1[o * 260 + k]; return; }
    id -= 67600;
    if (id < 67600) { int o = id % 260, k = id / 260; T2[k * 260 + o] = at5_w2[o * 260 + k]; return; }
    id -= 67600;
    if (id < 66560) { int o = id & 255, k = id >> 8; To1[k * 256 + o] = o1_w[o * 260 + k]; return; }
    id -= 66560;
    if (id < 65536) { int o = id & 255, k = id >> 8; To2[k * 256 + o] = o2_w[o * 256 + k]; return; }
    id -= 65536;
    if (id < 1024) { int f = id & 3, k = id >> 2; To3[k * 4 + f] = o3_w[f * 256 + k]; }
    return;
  }
  // pm: pre_msg bf16 [64][2304][8]; senders(f 0..3) then receivers(f 0..3)
  {
    int b2 = b - 1239;                 // 576 blocks
    int slice = b2 / 9, ec = b2 % 9;
    __shared__ float xsl[192];
    if (threadIdx.x < 192) xsl[threadIdx.x] = x[slice * 192 + threadIdx.x];
    __syncthreads();
    int e = ec * 256 + threadIdx.x;    // < 2304
    bf16x8 v = {};
    if (e < Ee) {
      const float* rs = rel_send + (size_t)e * Nn;
      const float* rr = rel_rec + (size_t)e * Nn;
      float a[8] = {0.f, 0.f, 0.f, 0.f, 0.f, 0.f, 0.f, 0.f};
      for (int n = 0; n < Nn; ++n) {
        float sv = rs[n], rv = rr[n];
#pragma unroll
        for (int f = 0; f < 4; ++f) {
          a[f] = fmaf(sv, xsl[n * 4 + f], a[f]);
          a[4 + f] = fmaf(rv, xsl[n * 4 + f], a[4 + f]);
        }
      }
#pragma unroll
      for (int j = 0; j < 8; ++j) v[j] = (__bf16)a[j];
    }
    ((bf16x8*)pmout)[(size_t)slice * 2304 + e] = v;
  }
}

// 512 blocks x 6 node-rows each; LDS reads quad-vectorized (b128)
template<int MODE>
__global__ __launch_bounds__(256, 4)
void node_kernel(const float* __restrict__ g_agg, const __bf16* __restrict__ partb,
                 const float* __restrict__ x,
                 const float* __restrict__ T1, const float* __restrict__ T2,
                 const float* __restrict__ To1, const float* __restrict__ To2,
                 const float* __restrict__ To3, const float* __restrict__ at5_b1,
                 const float* __restrict__ at5_b2, const float* __restrict__ at5_g,
                 const float* __restrict__ at5_be, const float* __restrict__ o1_b,
                 const float* __restrict__ o2_b, const float* __restrict__ o3_b,
                 float* __restrict__ out) {
  __shared__ __align__(16) float bufA[6 * 264], bufB[6 * 264];
  __shared__ float xres[6 * 4];
  const int tid = threadIdx.x;
  const int slice = blockIdx.x >> 3, rg = blockIdx.x & 7;
  const int n0 = rg * 6;
  for (int t = tid; t < 6 * 256; t += 256) {
    int r = t >> 8, h = t & 255;
    float s;
    if (MODE == 1) {
      s = 0.f;
#pragma unroll
      for (int sp = 0; sp < 4; ++sp)
        s += (float)partb[((((size_t)slice * 4 + sp) * Nn) + n0 + r) * Hh + h];
    } else {
      s = g_agg[(size_t)slice * 12288 + (size_t)(n0 + r) * 256 + h];
    }
    bufA[r * 264 + h] = s;
  }
  if (tid < 24) {
    int r = tid >> 2, f = tid & 3;
    float v = x[(size_t)slice * 192 + (n0 + r) * 4 + f];
    bufA[r * 264 + 256 + f] = v;
    xres[tid] = v;
  }
  __syncthreads();

  auto layer = [&](const float* WT, const float* bsrc, const float* in, float* outb,
                   int K, int O, int act, const float* gsc, const float* gbe) {
    for (int o = tid; o < O; o += 256) {
      float a[6];
      float bb = bsrc[o];
#pragma unroll
      for (int r = 0; r < 6; ++r) a[r] = bb;
      for (int k = 0; k < K; k += 4) {
        float w0 = WT[k * O + o], w1 = WT[(k + 1) * O + o];
        float w2 = WT[(k + 2) * O + o], w3 = WT[(k + 3) * O + o];
#pragma unroll
        for (int r = 0; r < 6; ++r) {
          f32x4 iv = *(const f32x4*)(in + r * 264 + k);
          a[r] = fmaf(iv[0], w0, a[r]);
          a[r] = fmaf(iv[1], w1, a[r]);
          a[r] = fmaf(iv[2], w2, a[r]);
          a[r] = fmaf(iv[3], w3, a[r]);
        }
      }
      float scv = 1.f, bev = 0.f;
      if (act == 2) { scv = gsc[o] * BN_RS; bev = gbe[o]; }
#pragma unroll
      for (int r = 0; r < 6; ++r) {
        float v = a[r];
        v = (act == 0) ? fmaxf(v, 0.f) : eluf(v);
        if (act == 2) v = v * scv + bev;
        outb[r * 264 + o] = v;
      }
    }
    __syncthreads();
  };

  layer(T1, at5_b1, bufA, bufB, 260, 260, 1, nullptr, nullptr);
  layer(T2, at5_b2, bufB, bufA, 260, 260, 2, at5_g, at5_be);
  layer(To1, o1_b, bufA, bufB, 260, 256, 0, nullptr, nullptr);
  layer(To2, o2_b, bufB, bufA, 256, 256, 0, nullptr, nullptr);
  if (tid < 24) {
    int r = tid >> 2, f = tid & 3;
    float s = o3_b[f];
    for (int k = 0; k < 256; k += 4) {
      f32x4 iv = *(const f32x4*)(bufA + r * 264 + k);
      s = fmaf(iv[0], To3[k * 4 + f], s);
      s = fmaf(iv[1], To3[(k + 1) * 4 + f], s);
      s = fmaf(iv[2], To3[(k + 2) * 4 + f], s);
      s = fmaf(iv[3], To3[(k + 3) * 4 + f], s);
    }
    out[(size_t)slice * 192 + (n0 + r) * 4 + f] = xres[tid] + s;
  }
}

extern "C" void kernel_launch(void* const* d_in, const int* in_sizes, int n_in,
                              void* d_out, int out_size, void* d_ws, size_t ws_size,
                              hipStream_t stream) {
  const float* x = (const float*)d_in[0];
  const float* rel_rec = (const float*)d_in[1];
  const float* rel_send = (const float*)d_in[2];
  const float* rel_type = (const float*)d_in[3];
  const float* mf1_w = (const float*)d_in[4];
  const float* mf1_b = (const float*)d_in[5];
  const float* mf2_w = (const float*)d_in[6];
  const float* mf2_b = (const float*)d_in[7];
  const float* at1_w1 = (const float*)d_in[8];
  const float* at1_b1 = (const float*)d_in[9];
  const float* at1_w2 = (const float*)d_in[10];
  const float* at1_b2 = (const float*)d_in[11];
  const float* at1_g = (const float*)d_in[12];
  const float* at1_be = (const float*)d_in[13];
  const float* at5_w1 = (const float*)d_in[14];
  const float* at5_b1 = (const float*)d_in[15];
  const float* at5_w2 = (const float*)d_in[16];
  const float* at5_b2 = (const float*)d_in[17];
  const float* at5_g = (const float*)d_in[18];
  const float* at5_be = (const float*)d_in[19];
  const float* o1_w = (const float*)d_in[20];
  const float* o1_b = (const float*)d_in[21];
  const float* o2_w = (const float*)d_in[22];
  const float* o2_b = (const float*)d_in[23];
  const float* o3_w = (const float*)d_in[24];
  const float* o3_b = (const float*)d_in[25];

  char* ws = (char*)d_ws;
  __bf16* wf = (__bf16*)(ws + WS_WF);
  __bf16* rra = (__bf16*)(ws + WS_RRA);
  float* tnode = (float*)(ws + WS_TN);
  float* g_agg = (float*)(ws + WS_AGG);
  __bf16* partb = (__bf16*)(ws + WS_PB);

  const int mode = (ws_size >= WS_NEED1) ? 1 : 0;
  // MODE1: pm lives in the (unused) g_agg slot; MODE0: pm at WS_PB (partb unused)
  __bf16* pm = (mode == 1) ? (__bf16*)(ws + WS_AGG) : (__bf16*)(ws + WS_PB);

  prep_all<<<1815, 256, 0, stream>>>(mf2_w, at1_w1, at1_w2, mf1_w, mf1_b, rel_rec,
                                     rel_send, x, at5_w1, at5_w2, o1_w, o2_w, o3_w,
                                     wf, rra, pm, tnode);

  if (mode == 1) {
    hipFuncSetAttribute((const void*)edge_kernel<1>,
                        hipFuncAttributeMaxDynamicSharedMemorySize, LDS_EDGE_BYTES);
    edge_kernel<1><<<BT * 4, 1024, LDS_EDGE_BYTES, stream>>>(
        rel_type, mf2_b, at1_b1, at1_b2, at1_g, at1_be, wf, rra, pm, g_agg, partb);
    node_kernel<1><<<512, 256, 0, stream>>>(g_agg, partb, x, tnode, tnode + 67600,
                                            tnode + 135200, tnode + 201760, tnode + 267296,
                                            at5_b1, at5_b2, at5_g, at5_be,
                                            o1_b, o2_b, o3_b, (float*)d_out);
  } else {
    hipMemsetAsync(g_agg, 0, (size_t)BT * Nn * Hh * 4, stream);
    hipFuncSetAttribute((const void*)edge_kernel<0>,
                        hipFuncAttributeMaxDynamicSharedMemorySize, LDS_EDGE_BYTES);
    edge_kernel<0><<<BT * 4, 1024, LDS_EDGE_BYTES, stream>>>(
        rel_type, mf2_b, at1_b1, at1_b2, at1_g, at1_be, wf, rra, pm, g_agg, partb);
    node_kernel<0><<<512, 256, 0, stream>>>(g_agg, partb, x, tnode, tnode + 67600,
                                            tnode + 135200, tnode + 201760, tnode + 267296,
                                            at5_b1, at5_b2, at5_g, at5_be,
                                            o1_b, o2_b, o3_b, (float*)d_out);
  }
}

// Round 18
// 244.348 us; speedup vs baseline: 1.4947x; 1.1336x over previous
//
#include <hip/hip_runtime.h>
#include <hip/hip_bf16.h>
#include <math.h>

typedef __bf16 bf16x8 __attribute__((ext_vector_type(8)));
typedef __bf16 bf16x4 __attribute__((ext_vector_type(4)));
typedef float f32x4 __attribute__((ext_vector_type(4)));

#define MFMA16(a,b,c) __builtin_amdgcn_mfma_f32_16x16x32_bf16(a,b,c,0,0,0)

static constexpr int Nn = 48, Hh = 256;
static constexpr int Ee = 2256, BT = 64;
static constexpr int ETILE = 64, NTILES = 36;          // 36*64 = 2304 >= 2256
static constexpr float BN_RS = 0.9999950000374998f;    // 1/sqrt(1+1e-5)

// ---- ws layout (bytes) ----
static constexpr size_t WS_WF  = 0;         // 4 mats frag-linear + mf1 frags: 557056
static constexpr size_t WS_RRA = 557056;    // 36*2*3*64*8 bf16 = 221184
static constexpr size_t WS_TN  = 778240;    // 268320 f32 = 1073280
static constexpr size_t WS_AGG = 1851520;   // MODE0: g_agg f32 3145728 | MODE1: pm bf16 2359296
static constexpr size_t WS_PB  = 4997248;   // MODE1: bf16 partials 6291456 | MODE0: pm
static constexpr size_t WS_NEED1 = WS_PB + 6291456;  // 11288704

// ---- LDS layout (bytes), total 137728; 1024 threads, 1 block/CU ----
static constexpr int LDS_ACT = 0;        // [64][512B] swizzled act
static constexpr int LDS_ALM = 32768;    // [64][512B] all_msgs act, then h_edges B-frags
static constexpr int LDS_WSG = 65536;    // 2 x 32KB ring of weight chunks (wave-private rows)
static constexpr int LDS_RT  = 131072;   // [64][2] f32
static constexpr int LDS_BS  = 131584;   // 1536 f32 biases
static constexpr int LDS_EDGE_BYTES = 137728;

__device__ __forceinline__ float eluf(float v) { return v > 0.f ? v : __expf(v) - 1.f; }

typedef __attribute__((address_space(1))) const unsigned int as1_uint;
typedef __attribute__((address_space(3))) unsigned int as3_uint;
__device__ __forceinline__ void gload16(const void* g, void* l) {
  __builtin_amdgcn_global_load_lds((as1_uint*)g, (as3_uint*)l, 16, 0, 0);
}

__device__ __forceinline__ int aoff(int e, int colbyte) {
  return e * 512 + (colbyte ^ ((e & 7) << 4));
}

// lgkm-only barrier: LDS writes visible, DMA (vmcnt) stays in flight (T4).
#define LBAR() do { asm volatile("s_waitcnt lgkmcnt(0)" ::: "memory"); \
  __builtin_amdgcn_s_barrier(); __builtin_amdgcn_sched_barrier(0); } while (0)
// per-wave counted DMA wait: all but the 2 newest outstanding vmem ops retired.
#define VWAIT2() do { asm volatile("s_waitcnt vmcnt(2)" ::: "memory"); \
  __builtin_amdgcn_sched_barrier(0); } while (0)

// wave wv stages ONLY its own B rows {wv, wv+16} of a 32KB chunk (wave-private).
__device__ __forceinline__ void issueW(const char* chunkSrc, char* wsgbuf, int wv, int lane) {
  gload16(chunkSrc + wv * 1024 + lane * 16, wsgbuf + wv * 1024);
  gload16(chunkSrc + (16 + wv) * 1024 + lane * 16, wsgbuf + (16 + wv) * 1024);
}

// K=256 GEMM, 16-wave 1Mx16N split, wave-private software-pipelined weight DMA.
// SW=true: operand-swapped (weights=A, act=B) -> C[out][edge]: thread holds 4
// consecutive OUT cols for one edge -> vectorizable bf16x4 epilogue writes.
// SW=false: original orientation (act=A) -> C[edge][out] (used by at1_l2 whose
// epilogue writes agg B-frags). Reads are IDENTICAL either way.
template<bool SW>
__device__ __forceinline__ void gemmK(char* smem, const char* wmat, const char* nextw,
                                      int abase, int lane, int wv, f32x4 acc[4]) {
  char* wsg = smem + LDS_WSG;
  const int kgb = (lane >> 4) * 16;
  const int c16 = lane & 15;
#pragma unroll
  for (int c = 0; c < 4; ++c) {
    VWAIT2();  // chunk c landed (this wave's rows)
#pragma unroll
    for (int ks = 0; ks < 2; ++ks) {
      const int kt = c * 2 + ks;
      bf16x8 bfr = *(const bf16x8*)(wsg + (c & 1) * 32768 + ((ks * 16 + wv) * 64 + lane) * 16);
#pragma unroll
      for (int t = 0; t < 4; ++t) {
        int r = t * 16 + c16;
        bf16x8 af = *(const bf16x8*)(smem + abase + r * 512 + ((kt * 64 + kgb) ^ ((r & 7) << 4)));
        acc[t] = SW ? MFMA16(bfr, af, acc[t]) : MFMA16(af, bfr, acc[t]);
      }
    }
    __builtin_amdgcn_sched_barrier(0);  // keep re-issue below the ds_reads above
    const char* src = (c < 2) ? (wmat + (c + 2) * 32768) : (nextw + (c - 2) * 32768);
    issueW(src, wsg + (c & 1) * 32768, wv, lane);
  }
}

template<int MODE>
__global__ __launch_bounds__(1024)
void edge_kernel(const float* __restrict__ rel_type,
                 const float* __restrict__ mf2_b, const float* __restrict__ at1_b1,
                 const float* __restrict__ at1_b2, const float* __restrict__ at1_g,
                 const float* __restrict__ at1_be, const __bf16* __restrict__ wf,
                 const __bf16* __restrict__ rra, const __bf16* __restrict__ pmsg,
                 float* __restrict__ g_agg, __bf16* __restrict__ partb) {
  extern __shared__ char smem[];
  float* rt = (float*)(smem + LDS_RT);
  float* bs = (float*)(smem + LDS_BS);
  const char* wfb = (const char*)wf;

  const int tid = threadIdx.x;
  const int lane = tid & 63;
  const int wv = tid >> 6;                // 0..15
  const int lg = lane >> 4;
  const int col16 = lane & 15;
  const int slice = blockIdx.x >> 2;
  const int split = blockIdx.x & 3;
  const int t_begin = split * 9;

  // block-start: bias table (resolves before the DMA pipeline starts)
#pragma unroll
  for (int i = 0; i < 2; ++i) {
    int t = i * 1024 + tid;
    if (t < 1536) {
      int which = t >> 8, o = t & 255;
      float v;
      switch (which) {
        case 0: v = mf2_b[o]; break;
        case 1: v = mf2_b[256 + o]; break;
        case 2: v = at1_b1[o]; break;
        case 3: v = at1_b2[o]; break;
        case 4: v = at1_g[o] * BN_RS; break;
        default: v = at1_be[o]; break;
      }
      bs[t] = v;
    }
  }
  // fc1 B-operand constant for k-groups 1..3 (bias 1.0 at k=8, zero pad)
  bf16x8 cst = {};
  if (lg == 1) cst[0] = (__bf16)1.0f;

  // start the cross-GEMM DMA pipeline: mf2_0 chunks 0,1 (this wave's rows)
  issueW(wfb, smem + LDS_WSG, wv, lane);
  issueW(wfb + 32768, smem + LDS_WSG + 32768, wv, lane);

  f32x4 ag[3];
#pragma unroll
  for (int a = 0; a < 3; ++a) ag[a] = (f32x4){0.f, 0.f, 0.f, 0.f};
  LBAR();

  const int cbw = (wv * 16 + lg * 4) * 2;   // byte col of this thread's 4 outs

  for (int tt = 0; tt < 9; ++tt) {
    const int tile = t_begin + tt;
    const int e0 = tile * ETILE;
    const int ne = (Ee - e0 < ETILE) ? (Ee - e0) : ETILE;

    // rt -> LDS (visible at the post-fc1 LBAR; epilogue reads it after that)
    if (tid < ETILE * 2) {
      int e = tid >> 1, i2 = tid & 1;
      rt[tid] = (e < ne) ? rel_type[((size_t)slice * Ee + e0 + e) * 2 + i2] : 0.f;
    }

#pragma unroll 1
    for (int ty = 0; ty < 2; ++ty) {
      {
        // fc1 (swapped): A = mf1 frags (outs), B = pm (edges, bias folded at k=8)
        bf16x8 pmv[4];
        if (lg == 0) {
#pragma unroll
          for (int nt = 0; nt < 4; ++nt)
            pmv[nt] = *(const bf16x8*)(pmsg + ((size_t)slice * 2304 + e0 + nt * 16 + col16) * 8);
        }
        bf16x8 wb = *(const bf16x8*)(wfb + 524288 + ty * 16384 +
                                     ((size_t)(wv * 64 + lane)) * 16);
        f32x4 fa[4];
#pragma unroll
        for (int nt = 0; nt < 4; ++nt) fa[nt] = (f32x4){0.f, 0.f, 0.f, 0.f};
#pragma unroll
        for (int nt = 0; nt < 4; ++nt) {
          bf16x8 bop = (lg == 0) ? pmv[nt] : cst;
          fa[nt] = MFMA16(wb, bop, fa[nt]);
        }
#pragma unroll
        for (int nt = 0; nt < 4; ++nt) {
          int e = nt * 16 + col16;
          bf16x4 pk;
#pragma unroll
          for (int r = 0; r < 4; ++r) pk[r] = (__bf16)fmaxf(fa[nt][r], 0.f);
          *(bf16x4*)(smem + LDS_ACT + aoff(e, cbw)) = pk;
        }
      }
      LBAR();  // ACT + rt visible to all waves

      f32x4 acc[4];
#pragma unroll
      for (int nt = 0; nt < 4; ++nt) acc[nt] = (f32x4){0.f, 0.f, 0.f, 0.f};
      const char* wm = wfb + (size_t)ty * 131072;
      const char* nx = wfb + (size_t)(ty + 1) * 131072;  // mf2_1 then at1_w1
      gemmK<true>(smem, wm, nx, LDS_ACT, lane, wv, acc);
      f32x4 bb4 = *(const f32x4*)(bs + ty * 256 + wv * 16 + lg * 4);
#pragma unroll
      for (int nt = 0; nt < 4; ++nt) {
        int e = nt * 16 + col16;
        float rtv = rt[e * 2 + ty];
        bf16x4* p = (bf16x4*)(smem + LDS_ALM + aoff(e, cbw));
        bf16x4 pk;
        if (ty == 1) {
          bf16x4 prev = *p;  // own patch: same thread wrote it at ty=0
#pragma unroll
          for (int r = 0; r < 4; ++r)
            pk[r] = (__bf16)(fmaxf(acc[nt][r] + bb4[r], 0.f) * rtv + (float)prev[r]);
        } else {
#pragma unroll
          for (int r = 0; r < 4; ++r)
            pk[r] = (__bf16)(fmaxf(acc[nt][r] + bb4[r], 0.f) * rtv);
        }
        *p = pk;
      }
      LBAR();  // epilogue done: ACT free for next fc1 / ALM visible for at1_l1
    }

    // at1_l1 (swapped): ALM @ W -> elu -> ACT
    {
      f32x4 acc[4];
#pragma unroll
      for (int nt = 0; nt < 4; ++nt) acc[nt] = (f32x4){0.f, 0.f, 0.f, 0.f};
      gemmK<true>(smem, wfb + (size_t)2 * 131072, wfb + (size_t)3 * 131072, LDS_ALM,
                  lane, wv, acc);
      f32x4 bb4 = *(const f32x4*)(bs + 512 + wv * 16 + lg * 4);
#pragma unroll
      for (int nt = 0; nt < 4; ++nt) {
        int e = nt * 16 + col16;
        bf16x4 pk;
#pragma unroll
        for (int r = 0; r < 4; ++r) pk[r] = (__bf16)eluf(acc[nt][r] + bb4[r]);
        *(bf16x4*)(smem + LDS_ACT + aoff(e, cbw)) = pk;
      }
    }
    LBAR();  // ACT(elu) visible; all waves out of l1-gemm

    // at1_l2 (original orientation): ACT @ W -> elu*sc+be -> h_edges B-frags in ALM
    {
      f32x4 acc[4];
#pragma unroll
      for (int mt = 0; mt < 4; ++mt) acc[mt] = (f32x4){0.f, 0.f, 0.f, 0.f};
      gemmK<false>(smem, wfb + (size_t)3 * 131072, wfb, LDS_ACT, lane, wv, acc);  // next: mf2_0
      const int col = wv * 16 + col16;
      const float b_ = bs[768 + col], s1 = bs[1024 + col], s2 = bs[1280 + col];
      const int j0 = (lg & 1) * 4;
#pragma unroll
      for (int mt = 0; mt < 4; ++mt) {
        const int khalf = mt >> 1;
        const int lane2 = col16 | ((((mt & 1) * 2) + (lg >> 1)) << 4);
        bf16x4 pk;
#pragma unroll
        for (int r = 0; r < 4; ++r)
          pk[r] = (__bf16)(eluf(acc[mt][r] + b_) * s1 + s2);
        int addr = (((khalf * 16 + wv) * 64 + lane2) * 8 + j0) * 2;
        *(bf16x4*)(smem + LDS_ALM + addr) = pk;
      }
    }
    LBAR();  // B-frags visible; all waves out of l2-gemm

    // agg GEMM: ag += rel_rec[tile]^T @ h_edges  (M=48, N=256, K=64)
    const bf16x8* rraw = (const bf16x8*)rra + (size_t)tile * 384;
#pragma unroll
    for (int kt2 = 0; kt2 < 2; ++kt2) {
      bf16x8 b = *(const bf16x8*)(smem + LDS_ALM + ((kt2 * 16 + wv) * 64 + lane) * 16);
#pragma unroll
      for (int mt2 = 0; mt2 < 3; ++mt2) {
        bf16x8 a = rraw[(kt2 * 3 + mt2) * 64 + lane];
        ag[mt2] = MFMA16(a, b, ag[mt2]);
      }
    }
    // next tile's fc1 writes ACT (disjoint); post-fc1 LBAR gates ALM overwrite
  }

  if (MODE == 1) {
    __bf16* dst = partb + (size_t)blockIdx.x * Nn * Hh;
    const int h = wv * 16 + col16;
#pragma unroll
    for (int mt2 = 0; mt2 < 3; ++mt2)
#pragma unroll
      for (int r = 0; r < 4; ++r) {
        int n = mt2 * 16 + lg * 4 + r;
        dst[n * Hh + h] = (__bf16)ag[mt2][r];
      }
  } else {
    float* dst = g_agg + (size_t)slice * Nn * Hh;
    const int h = wv * 16 + col16;
#pragma unroll
    for (int mt2 = 0; mt2 < 3; ++mt2)
#pragma unroll
      for (int r = 0; r < 4; ++r) {
        int n = mt2 * 16 + lg * 4 + r;
        atomicAdd(dst + n * Hh + h, ag[mt2][r]);
      }
  }
}

// merged prep: [0,128) frag, [128,136) mf1, [136,190) rra, [190,1239) node
__global__ void prep_all(const float* __restrict__ mf2_w, const float* __restrict__ at1_w1,
                         const float* __restrict__ at1_w2, const float* __restrict__ mf1_w,
                         const float* __restrict__ mf1_b, const float* __restrict__ rel_rec,
                         const float* __restrict__ at5_w1, const float* __restrict__ at5_w2,
                         const float* __restrict__ o1_w, const float* __restrict__ o2_w,
                         const float* __restrict__ o3_w,
                         __bf16* __restrict__ wfdst, __bf16* __restrict__ rra,
                         float* __restrict__ tn) {
  int b = blockIdx.x;
  if (b < 128) {
    int id = b * 256 + threadIdx.x;  // 32768
    int mat = id >> 13, r = id & 8191;
    int kt = r >> 10, q = r & 1023, nt = q >> 6, l = q & 63;
    int row = nt * 16 + (l & 15), col = kt * 32 + (l >> 4) * 8;
    const float* src = (mat == 0) ? mf2_w : (mat == 1) ? (mf2_w + 65536)
                     : (mat == 2) ? at1_w1 : at1_w2;
    const float* p = src + row * 256 + col;
    __bf16* d = wfdst + (size_t)mat * 65536 + ((size_t)(kt * 16 + nt) * 64 + l) * 8;
#pragma unroll
    for (int j = 0; j < 8; ++j) d[j] = (__bf16)p[j];
    return;
  }
  if (b < 136) {
    int id = (b - 128) * 256 + threadIdx.x;  // 2048
    int ty = id >> 10, q = id & 1023, ntg = q >> 6, l = q & 63;
    int col = ntg * 16 + (l & 15);
    int k0 = (l >> 4) * 8;
    bf16x8 v;
#pragma unroll
    for (int j = 0; j < 8; ++j) {
      int k = k0 + j;
      float xv = (k < 8) ? mf1_w[ty * 2048 + col * 8 + k]
               : (k == 8) ? mf1_b[ty * 256 + col] : 0.f;
      v[j] = (__bf16)xv;
    }
    ((bf16x8*)(wfdst + 262144))[id] = v;
    return;
  }
  if (b < 190) {
    int id = (b - 136) * 256 + threadIdx.x;  // 13824
    if (id >= 13824) return;
    int tile = id / 384, r = id % 384;
    int kt2 = r / 192, r2 = r % 192, mt2 = r2 >> 6, l = r2 & 63;
    int ebase = tile * 64 + kt2 * 32 + (l >> 4) * 8;
    int n = mt2 * 16 + (l & 15);
    bf16x8 v;
#pragma unroll
    for (int j = 0; j < 8; ++j) {
      int e = ebase + j;
      v[j] = (__bf16)((e < Ee) ? rel_rec[(size_t)e * Nn + n] : 0.f);
    }
    ((bf16x8*)rra)[id] = v;
    return;
  }
  int id = (b - 190) * 256 + threadIdx.x;
  float* T1 = tn;
  float* T2 = T1 + 67600;
  float* To1 = T2 + 67600;
  float* To2 = To1 + 66560;
  float* To3 = To2 + 65536;
  if (id < 67600) { int o = id % 260, k = id / 260; T1[k * 260 + o] = at5_w1[o * 260 + k]; return; }
  id -= 67600;
  if (id < 67600) { int o = id % 260, k = id / 260; T2[k * 260 + o] = at5_w2[o * 260 + k]; return; }
  id -= 67600;
  if (id < 66560) { int o = id & 255, k = id >> 8; To1[k * 256 + o] = o1_w[o * 260 + k]; return; }
  id -= 66560;
  if (id < 65536) { int o = id & 255, k = id >> 8; To2[k * 256 + o] = o2_w[o * 256 + k]; return; }
  id -= 65536;
  if (id < 1024) { int f = id & 3, k = id >> 2; To3[k * 4 + f] = o3_w[f * 256 + k]; }
}

// pm precompute with LDS-staged rel (coalesced; the global-scatter version thrashed L1).
// 64 slices x 18 segs of 128 edges; thread t: edge t&127, half t>>7 (send/recv).
__global__ __launch_bounds__(256)
void prep_pm(const float* __restrict__ rel_rec, const float* __restrict__ rel_send,
             const float* __restrict__ x, __bf16* __restrict__ pmout) {
  __shared__ float rs[128 * 48], rr[128 * 48], xsl[192];
  const int b = blockIdx.x;               // 1152
  const int slice = b / 18, seg = b % 18;
  const int e0 = seg * 128;
  const int nv = (Ee - e0 < 128) ? (Ee - e0) : 128;
  const int cnt = nv * 48;
  for (int t = threadIdx.x; t < cnt; t += 256) {
    rs[t] = rel_send[(size_t)e0 * 48 + t];
    rr[t] = rel_rec[(size_t)e0 * 48 + t];
  }
  if (threadIdx.x < 192) xsl[threadIdx.x] = x[slice * 192 + threadIdx.x];
  __syncthreads();
  const int el = threadIdx.x & 127, half = threadIdx.x >> 7;
  float a0 = 0.f, a1 = 0.f, a2 = 0.f, a3 = 0.f;
  if (el < nv) {
    const float* rel = half ? rr : rs;
    for (int n = 0; n < 48; ++n) {
      float v = rel[el * 48 + n];
      a0 = fmaf(v, xsl[n * 4 + 0], a0);
      a1 = fmaf(v, xsl[n * 4 + 1], a1);
      a2 = fmaf(v, xsl[n * 4 + 2], a2);
      a3 = fmaf(v, xsl[n * 4 + 3], a3);
    }
  }
  bf16x4 o;
  o[0] = (__bf16)a0; o[1] = (__bf16)a1; o[2] = (__bf16)a2; o[3] = (__bf16)a3;
  *(bf16x4*)(pmout + ((size_t)slice * 2304 + e0 + el) * 8 + half * 4) = o;
}

// 512 blocks x 6 node-rows each; LDS reads quad-vectorized (b128)
template<int MODE>
__global__ __launch_bounds__(256, 4)
void node_kernel(const float* __restrict__ g_agg, const __bf16* __restrict__ partb,
                 const float* __restrict__ x,
                 const float* __restrict__ T1, const float* __restrict__ T2,
                 const float* __restrict__ To1, const float* __restrict__ To2,
                 const float* __restrict__ To3, const float* __restrict__ at5_b1,
                 const float* __restrict__ at5_b2, const float* __restrict__ at5_g,
                 const float* __restrict__ at5_be, const float* __restrict__ o1_b,
                 const float* __restrict__ o2_b, const float* __restrict__ o3_b,
                 float* __restrict__ out) {
  __shared__ __align__(16) float bufA[6 * 264], bufB[6 * 264];
  __shared__ float xres[6 * 4];
  const int tid = threadIdx.x;
  const int slice = blockIdx.x >> 3, rg = blockIdx.x & 7;
  const int n0 = rg * 6;
  for (int t = tid; t < 6 * 256; t += 256) {
    int r = t >> 8, h = t & 255;
    float s;
    if (MODE == 1) {
      s = 0.f;
#pragma unroll
      for (int sp = 0; sp < 4; ++sp)
        s += (float)partb[((((size_t)slice * 4 + sp) * Nn) + n0 + r) * Hh + h];
    } else {
      s = g_agg[(size_t)slice * 12288 + (size_t)(n0 + r) * 256 + h];
    }
    bufA[r * 264 + h] = s;
  }
  if (tid < 24) {
    int r = tid >> 2, f = tid & 3;
    float v = x[(size_t)slice * 192 + (n0 + r) * 4 + f];
    bufA[r * 264 + 256 + f] = v;
    xres[tid] = v;
  }
  __syncthreads();

  auto layer = [&](const float* WT, const float* bsrc, const float* in, float* outb,
                   int K, int O, int act, const float* gsc, const float* gbe) {
    for (int o = tid; o < O; o += 256) {
      float a[6];
      float bb = bsrc[o];
#pragma unroll
      for (int r = 0; r < 6; ++r) a[r] = bb;
      for (int k = 0; k < K; k += 4) {
        float w0 = WT[k * O + o], w1 = WT[(k + 1) * O + o];
        float w2 = WT[(k + 2) * O + o], w3 = WT[(k + 3) * O + o];
#pragma unroll
        for (int r = 0; r < 6; ++r) {
          f32x4 iv = *(const f32x4*)(in + r * 264 + k);
          a[r] = fmaf(iv[0], w0, a[r]);
          a[r] = fmaf(iv[1], w1, a[r]);
          a[r] = fmaf(iv[2], w2, a[r]);
          a[r] = fmaf(iv[3], w3, a[r]);
        }
      }
      float scv = 1.f, bev = 0.f;
      if (act == 2) { scv = gsc[o] * BN_RS; bev = gbe[o]; }
#pragma unroll
      for (int r = 0; r < 6; ++r) {
        float v = a[r];
        v = (act == 0) ? fmaxf(v, 0.f) : eluf(v);
        if (act == 2) v = v * scv + bev;
        outb[r * 264 + o] = v;
      }
    }
    __syncthreads();
  };

  layer(T1, at5_b1, bufA, bufB, 260, 260, 1, nullptr, nullptr);
  layer(T2, at5_b2, bufB, bufA, 260, 260, 2, at5_g, at5_be);
  layer(To1, o1_b, bufA, bufB, 260, 256, 0, nullptr, nullptr);
  layer(To2, o2_b, bufB, bufA, 256, 256, 0, nullptr, nullptr);
  if (tid < 24) {
    int r = tid >> 2, f = tid & 3;
    float s = o3_b[f];
    for (int k = 0; k < 256; k += 4) {
      f32x4 iv = *(const f32x4*)(bufA + r * 264 + k);
      s = fmaf(iv[0], To3[k * 4 + f], s);
      s = fmaf(iv[1], To3[(k + 1) * 4 + f], s);
      s = fmaf(iv[2], To3[(k + 2) * 4 + f], s);
      s = fmaf(iv[3], To3[(k + 3) * 4 + f], s);
    }
    out[(size_t)slice * 192 + (n0 + r) * 4 + f] = xres[tid] + s;
  }
}

extern "C" void kernel_launch(void* const* d_in, const int* in_sizes, int n_in,
                              void* d_out, int out_size, void* d_ws, size_t ws_size,
                              hipStream_t stream) {
  const float* x = (const float*)d_in[0];
  const float* rel_rec = (const float*)d_in[1];
  const float* rel_send = (const float*)d_in[2];
  const float* rel_type = (const float*)d_in[3];
  const float* mf1_w = (const float*)d_in[4];
  const float* mf1_b = (const float*)d_in[5];
  const float* mf2_w = (const float*)d_in[6];
  const float* mf2_b = (const float*)d_in[7];
  const float* at1_w1 = (const float*)d_in[8];
  const float* at1_b1 = (const float*)d_in[9];
  const float* at1_w2 = (const float*)d_in[10];
  const float* at1_b2 = (const float*)d_in[11];
  const float* at1_g = (const float*)d_in[12];
  const float* at1_be = (const float*)d_in[13];
  const float* at5_w1 = (const float*)d_in[14];
  const float* at5_b1 = (const float*)d_in[15];
  const float* at5_w2 = (const float*)d_in[16];
  const float* at5_b2 = (const float*)d_in[17];
  const float* at5_g = (const float*)d_in[18];
  const float* at5_be = (const float*)d_in[19];
  const float* o1_w = (const float*)d_in[20];
  const float* o1_b = (const float*)d_in[21];
  const float* o2_w = (const float*)d_in[22];
  const float* o2_b = (const float*)d_in[23];
  const float* o3_w = (const float*)d_in[24];
  const float* o3_b = (const float*)d_in[25];

  char* ws = (char*)d_ws;
  __bf16* wf = (__bf16*)(ws + WS_WF);
  __bf16* rra = (__bf16*)(ws + WS_RRA);
  float* tnode = (float*)(ws + WS_TN);
  float* g_agg = (float*)(ws + WS_AGG);
  __bf16* partb = (__bf16*)(ws + WS_PB);

  const int mode = (ws_size >= WS_NEED1) ? 1 : 0;
  // MODE1: pm lives in the (unused) g_agg slot; MODE0: pm at WS_PB (partb unused)
  __bf16* pm = (mode == 1) ? (__bf16*)(ws + WS_AGG) : (__bf16*)(ws + WS_PB);

  prep_all<<<1239, 256, 0, stream>>>(mf2_w, at1_w1, at1_w2, mf1_w, mf1_b, rel_rec,
                                     at5_w1, at5_w2, o1_w, o2_w, o3_w, wf, rra, tnode);
  prep_pm<<<1152, 256, 0, stream>>>(rel_rec, rel_send, x, pm);

  if (mode == 1) {
    hipFuncSetAttribute((const void*)edge_kernel<1>,
                        hipFuncAttributeMaxDynamicSharedMemorySize, LDS_EDGE_BYTES);
    edge_kernel<1><<<BT * 4, 1024, LDS_EDGE_BYTES, stream>>>(
        rel_type, mf2_b, at1_b1, at1_b2, at1_g, at1_be, wf, rra, pm, g_agg, partb);
    node_kernel<1><<<512, 256, 0, stream>>>(g_agg, partb, x, tnode, tnode + 67600,
                                            tnode + 135200, tnode + 201760, tnode + 267296,
                                            at5_b1, at5_b2, at5_g, at5_be,
                                            o1_b, o2_b, o3_b, (float*)d_out);
  } else {
    hipMemsetAsync(g_agg, 0, (size_t)BT * Nn * Hh * 4, stream);
    hipFuncSetAttribute((const void*)edge_kernel<0>,
                        hipFuncAttributeMaxDynamicSharedMemorySize, LDS_EDGE_BYTES);
    edge_kernel<0><<<BT * 4, 1024, LDS_EDGE_BYTES, stream>>>(
        rel_type, mf2_b, at1_b1, at1_b2, at1_g, at1_be, wf, rra, pm, g_agg, partb);
    node_kernel<0><<<512, 256, 0, stream>>>(g_agg, partb, x, tnode, tnode + 67600,
                                            tnode + 135200, tnode + 201760, tnode + 267296,
                                            at5_b1, at5_b2, at5_g, at5_be,
                                            o1_b, o2_b, o3_b, (float*)d_out);
  }
}

// Round 19
// 209.188 us; speedup vs baseline: 1.7459x; 1.1681x over previous
//
#include <hip/hip_runtime.h>
#include <hip/hip_bf16.h>
#include <math.h>

typedef __bf16 bf16x8 __attribute__((ext_vector_type(8)));
typedef __bf16 bf16x4 __attribute__((ext_vector_type(4)));
typedef float f32x4 __attribute__((ext_vector_type(4)));

#define MFMA16(a,b,c) __builtin_amdgcn_mfma_f32_16x16x32_bf16(a,b,c,0,0,0)

static constexpr int Nn = 48, Hh = 256;
static constexpr int Ee = 2256, BT = 64;
static constexpr int ETILE = 64, NTILES = 36;          // 36*64 = 2304 >= 2256
static constexpr float BN_RS = 0.9999950000374998f;    // 1/sqrt(1+1e-5)

// ---- ws layout (bytes) ----
static constexpr size_t WS_WF  = 0;         // 4 mats frag-linear + mf1 frags: 557056
static constexpr size_t WS_RRA = 557056;    // 36*2*3*64*8 bf16 = 221184
static constexpr size_t WS_TN  = 778240;    // 268320 f32 = 1073280
static constexpr size_t WS_AGG = 1851520;   // MODE0: g_agg f32 3145728 | MODE1: pm bf16 2359296
static constexpr size_t WS_PB  = 4997248;   // MODE1: bf16 partials 6291456 | MODE0: pm
static constexpr size_t WS_NEED1 = WS_PB + 6291456;  // 11288704

// ---- LDS layout (bytes), total 137728; 1024 threads, 1 block/CU ----
static constexpr int LDS_ACT = 0;        // [64][512B] swizzled act
static constexpr int LDS_ALM = 32768;    // [64][512B] all_msgs act, then h_edges B-frags
static constexpr int LDS_WSG = 65536;    // 2 x 32KB ring of weight chunks (wave-private rows)
static constexpr int LDS_RT  = 131072;   // [64][2] f32
static constexpr int LDS_BS  = 131584;   // 1536 f32 biases
static constexpr int LDS_EDGE_BYTES = 137728;

__device__ __forceinline__ float eluf(float v) { return v > 0.f ? v : __expf(v) - 1.f; }

typedef __attribute__((address_space(1))) const unsigned int as1_uint;
typedef __attribute__((address_space(3))) unsigned int as3_uint;
__device__ __forceinline__ void gload16(const void* g, void* l) {
  __builtin_amdgcn_global_load_lds((as1_uint*)g, (as3_uint*)l, 16, 0, 0);
}

__device__ __forceinline__ int aoff(int e, int colbyte) {
  return e * 512 + (colbyte ^ ((e & 7) << 4));
}

// lgkm-only barrier: LDS writes visible, DMA (vmcnt) stays in flight (T4).
#define LBAR() do { asm volatile("s_waitcnt lgkmcnt(0)" ::: "memory"); \
  __builtin_amdgcn_s_barrier(); __builtin_amdgcn_sched_barrier(0); } while (0)
// per-wave counted DMA wait: all but the 2 newest outstanding vmem ops retired.
#define VWAIT2() do { asm volatile("s_waitcnt vmcnt(2)" ::: "memory"); \
  __builtin_amdgcn_sched_barrier(0); } while (0)

// wave wv stages ONLY its own B rows {wv, wv+16} of a 32KB chunk (wave-private).
__device__ __forceinline__ void issueW(const char* chunkSrc, char* wsgbuf, int wv, int lane) {
  gload16(chunkSrc + wv * 1024 + lane * 16, wsgbuf + wv * 1024);
  gload16(chunkSrc + (16 + wv) * 1024 + lane * 16, wsgbuf + (16 + wv) * 1024);
}

// K=256 GEMM, 16-wave 1Mx16N split, wave-private software-pipelined weight DMA.
// SW=true: operand-swapped (weights=A, act=B) -> C[out][edge]: thread holds 4
// consecutive OUT cols for one edge -> vectorizable bf16x4 epilogue writes.
// SW=false: original orientation (act=A) -> C[edge][out] (at1_l2's agg B-frag epi).
template<bool SW>
__device__ __forceinline__ void gemmK(char* smem, const char* wmat, const char* nextw,
                                      int abase, int lane, int wv, f32x4 acc[4]) {
  char* wsg = smem + LDS_WSG;
  const int kgb = (lane >> 4) * 16;
  const int c16 = lane & 15;
#pragma unroll
  for (int c = 0; c < 4; ++c) {
    VWAIT2();  // chunk c landed (this wave's rows)
#pragma unroll
    for (int ks = 0; ks < 2; ++ks) {
      const int kt = c * 2 + ks;
      bf16x8 bfr = *(const bf16x8*)(wsg + (c & 1) * 32768 + ((ks * 16 + wv) * 64 + lane) * 16);
#pragma unroll
      for (int t = 0; t < 4; ++t) {
        int r = t * 16 + c16;
        bf16x8 af = *(const bf16x8*)(smem + abase + r * 512 + ((kt * 64 + kgb) ^ ((r & 7) << 4)));
        acc[t] = SW ? MFMA16(bfr, af, acc[t]) : MFMA16(af, bfr, acc[t]);
      }
    }
    __builtin_amdgcn_sched_barrier(0);  // keep re-issue below the ds_reads above
    const char* src = (c < 2) ? (wmat + (c + 2) * 32768) : (nextw + (c - 2) * 32768);
    issueW(src, wsg + (c & 1) * 32768, wv, lane);
  }
}

template<int MODE>
__global__ __launch_bounds__(1024)
void edge_kernel(const float* __restrict__ rel_type,
                 const float* __restrict__ mf2_b, const float* __restrict__ at1_b1,
                 const float* __restrict__ at1_b2, const float* __restrict__ at1_g,
                 const float* __restrict__ at1_be, const __bf16* __restrict__ wf,
                 const __bf16* __restrict__ rra, const __bf16* __restrict__ pmsg,
                 float* __restrict__ g_agg, __bf16* __restrict__ partb) {
  extern __shared__ char smem[];
  float* rt = (float*)(smem + LDS_RT);
  float* bs = (float*)(smem + LDS_BS);
  const char* wfb = (const char*)wf;

  const int tid = threadIdx.x;
  const int lane = tid & 63;
  const int wv = tid >> 6;                // 0..15
  const int lg = lane >> 4;
  const int col16 = lane & 15;
  const int slice = blockIdx.x >> 2;
  const int split = blockIdx.x & 3;
  const int t_begin = split * 9;

  // block-start: bias table (resolves before the DMA pipeline starts)
#pragma unroll
  for (int i = 0; i < 2; ++i) {
    int t = i * 1024 + tid;
    if (t < 1536) {
      int which = t >> 8, o = t & 255;
      float v;
      switch (which) {
        case 0: v = mf2_b[o]; break;
        case 1: v = mf2_b[256 + o]; break;
        case 2: v = at1_b1[o]; break;
        case 3: v = at1_b2[o]; break;
        case 4: v = at1_g[o] * BN_RS; break;
        default: v = at1_be[o]; break;
      }
      bs[t] = v;
    }
  }
  // fc1 B-operand constant for k-groups 1..3 (bias 1.0 at k=8, zero pad)
  bf16x8 cst = {};
  if (lg == 1) cst[0] = (__bf16)1.0f;

  // start the cross-GEMM DMA pipeline: mf2_0 chunks 0,1 (this wave's rows)
  issueW(wfb, smem + LDS_WSG, wv, lane);
  issueW(wfb + 32768, smem + LDS_WSG + 32768, wv, lane);

  f32x4 ag[3];
#pragma unroll
  for (int a = 0; a < 3; ++a) ag[a] = (f32x4){0.f, 0.f, 0.f, 0.f};
  LBAR();

  const int cbw = (wv * 16 + lg * 4) * 2;   // byte col of this thread's 4 outs

  for (int tt = 0; tt < 9; ++tt) {
    const int tile = t_begin + tt;
    const int e0 = tile * ETILE;
    const int ne = (Ee - e0 < ETILE) ? (Ee - e0) : ETILE;

    // rt -> LDS (visible at the post-fc1 LBAR; epilogue reads it after that)
    if (tid < ETILE * 2) {
      int e = tid >> 1, i2 = tid & 1;
      rt[tid] = (e < ne) ? rel_type[((size_t)slice * Ee + e0 + e) * 2 + i2] : 0.f;
    }

#pragma unroll 1
    for (int ty = 0; ty < 2; ++ty) {
      {
        // fc1 (swapped): A = mf1 frags (outs), B = pm (edges, bias folded at k=8)
        bf16x8 pmv[4];
        if (lg == 0) {
#pragma unroll
          for (int nt = 0; nt < 4; ++nt)
            pmv[nt] = *(const bf16x8*)(pmsg + ((size_t)slice * 2304 + e0 + nt * 16 + col16) * 8);
        }
        bf16x8 wb = *(const bf16x8*)(wfb + 524288 + ty * 16384 +
                                     ((size_t)(wv * 64 + lane)) * 16);
        f32x4 fa[4];
#pragma unroll
        for (int nt = 0; nt < 4; ++nt) fa[nt] = (f32x4){0.f, 0.f, 0.f, 0.f};
#pragma unroll
        for (int nt = 0; nt < 4; ++nt) {
          bf16x8 bop = (lg == 0) ? pmv[nt] : cst;
          fa[nt] = MFMA16(wb, bop, fa[nt]);
        }
#pragma unroll
        for (int nt = 0; nt < 4; ++nt) {
          int e = nt * 16 + col16;
          bf16x4 pk;
#pragma unroll
          for (int r = 0; r < 4; ++r) pk[r] = (__bf16)fmaxf(fa[nt][r], 0.f);
          *(bf16x4*)(smem + LDS_ACT + aoff(e, cbw)) = pk;
        }
      }
      LBAR();  // ACT + rt visible to all waves

      f32x4 acc[4];
#pragma unroll
      for (int nt = 0; nt < 4; ++nt) acc[nt] = (f32x4){0.f, 0.f, 0.f, 0.f};
      const char* wm = wfb + (size_t)ty * 131072;
      const char* nx = wfb + (size_t)(ty + 1) * 131072;  // mf2_1 then at1_w1
      gemmK<true>(smem, wm, nx, LDS_ACT, lane, wv, acc);
      f32x4 bb4 = *(const f32x4*)(bs + ty * 256 + wv * 16 + lg * 4);
#pragma unroll
      for (int nt = 0; nt < 4; ++nt) {
        int e = nt * 16 + col16;
        float rtv = rt[e * 2 + ty];
        bf16x4* p = (bf16x4*)(smem + LDS_ALM + aoff(e, cbw));
        bf16x4 pk;
        if (ty == 1) {
          bf16x4 prev = *p;  // own patch: same thread wrote it at ty=0
#pragma unroll
          for (int r = 0; r < 4; ++r)
            pk[r] = (__bf16)(fmaxf(acc[nt][r] + bb4[r], 0.f) * rtv + (float)prev[r]);
        } else {
#pragma unroll
          for (int r = 0; r < 4; ++r)
            pk[r] = (__bf16)(fmaxf(acc[nt][r] + bb4[r], 0.f) * rtv);
        }
        *p = pk;
      }
      LBAR();  // epilogue done: ACT free for next fc1 / ALM visible for at1_l1
    }

    // at1_l1 (swapped): ALM @ W -> elu -> ACT
    {
      f32x4 acc[4];
#pragma unroll
      for (int nt = 0; nt < 4; ++nt) acc[nt] = (f32x4){0.f, 0.f, 0.f, 0.f};
      gemmK<true>(smem, wfb + (size_t)2 * 131072, wfb + (size_t)3 * 131072, LDS_ALM,
                  lane, wv, acc);
      f32x4 bb4 = *(const f32x4*)(bs + 512 + wv * 16 + lg * 4);
#pragma unroll
      for (int nt = 0; nt < 4; ++nt) {
        int e = nt * 16 + col16;
        bf16x4 pk;
#pragma unroll
        for (int r = 0; r < 4; ++r) pk[r] = (__bf16)eluf(acc[nt][r] + bb4[r]);
        *(bf16x4*)(smem + LDS_ACT + aoff(e, cbw)) = pk;
      }
    }
    LBAR();  // ACT(elu) visible; all waves out of l1-gemm

    // at1_l2 (original orientation): ACT @ W -> elu*sc+be -> h_edges B-frags in ALM
    {
      f32x4 acc[4];
#pragma unroll
      for (int mt = 0; mt < 4; ++mt) acc[mt] = (f32x4){0.f, 0.f, 0.f, 0.f};
      gemmK<false>(smem, wfb + (size_t)3 * 131072, wfb, LDS_ACT, lane, wv, acc);  // next: mf2_0
      const int col = wv * 16 + col16;
      const float b_ = bs[768 + col], s1 = bs[1024 + col], s2 = bs[1280 + col];
      const int j0 = (lg & 1) * 4;
#pragma unroll
      for (int mt = 0; mt < 4; ++mt) {
        const int khalf = mt >> 1;
        const int lane2 = col16 | ((((mt & 1) * 2) + (lg >> 1)) << 4);
        bf16x4 pk;
#pragma unroll
        for (int r = 0; r < 4; ++r)
          pk[r] = (__bf16)(eluf(acc[mt][r] + b_) * s1 + s2);
        int addr = (((khalf * 16 + wv) * 64 + lane2) * 8 + j0) * 2;
        *(bf16x4*)(smem + LDS_ALM + addr) = pk;
      }
    }
    LBAR();  // B-frags visible; all waves out of l2-gemm

    // agg GEMM: ag += rel_rec[tile]^T @ h_edges  (M=48, N=256, K=64)
    const bf16x8* rraw = (const bf16x8*)rra + (size_t)tile * 384;
#pragma unroll
    for (int kt2 = 0; kt2 < 2; ++kt2) {
      bf16x8 b = *(const bf16x8*)(smem + LDS_ALM + ((kt2 * 16 + wv) * 64 + lane) * 16);
#pragma unroll
      for (int mt2 = 0; mt2 < 3; ++mt2) {
        bf16x8 a = rraw[(kt2 * 3 + mt2) * 64 + lane];
        ag[mt2] = MFMA16(a, b, ag[mt2]);
      }
    }
    // next tile's fc1 writes ACT (disjoint); post-fc1 LBAR gates ALM overwrite
  }

  if (MODE == 1) {
    __bf16* dst = partb + (size_t)blockIdx.x * Nn * Hh;
    const int h = wv * 16 + col16;
#pragma unroll
    for (int mt2 = 0; mt2 < 3; ++mt2)
#pragma unroll
      for (int r = 0; r < 4; ++r) {
        int n = mt2 * 16 + lg * 4 + r;
        dst[n * Hh + h] = (__bf16)ag[mt2][r];
      }
  } else {
    float* dst = g_agg + (size_t)slice * Nn * Hh;
    const int h = wv * 16 + col16;
#pragma unroll
    for (int mt2 = 0; mt2 < 3; ++mt2)
#pragma unroll
      for (int r = 0; r < 4; ++r) {
        int n = mt2 * 16 + lg * 4 + r;
        atomicAdd(dst + n * Hh + h, ag[mt2][r]);
      }
  }
}

// merged prep: [0,128) frag, [128,136) mf1, [136,190) rra, [190,1239) node
__global__ void prep_all(const float* __restrict__ mf2_w, const float* __restrict__ at1_w1,
                         const float* __restrict__ at1_w2, const float* __restrict__ mf1_w,
                         const float* __restrict__ mf1_b, const float* __restrict__ rel_rec,
                         const float* __restrict__ at5_w1, const float* __restrict__ at5_w2,
                         const float* __restrict__ o1_w, const float* __restrict__ o2_w,
                         const float* __restrict__ o3_w,
                         __bf16* __restrict__ wfdst, __bf16* __restrict__ rra,
                         float* __restrict__ tn) {
  int b = blockIdx.x;
  if (b < 128) {
    int id = b * 256 + threadIdx.x;  // 32768
    int mat = id >> 13, r = id & 8191;
    int kt = r >> 10, q = r & 1023, nt = q >> 6, l = q & 63;
    int row = nt * 16 + (l & 15), col = kt * 32 + (l >> 4) * 8;
    const float* src = (mat == 0) ? mf2_w : (mat == 1) ? (mf2_w + 65536)
                     : (mat == 2) ? at1_w1 : at1_w2;
    const float* p = src + row * 256 + col;
    __bf16* d = wfdst + (size_t)mat * 65536 + ((size_t)(kt * 16 + nt) * 64 + l) * 8;
#pragma unroll
    for (int j = 0; j < 8; ++j) d[j] = (__bf16)p[j];
    return;
  }
  if (b < 136) {
    int id = (b - 128) * 256 + threadIdx.x;  // 2048
    int ty = id >> 10, q = id & 1023, ntg = q >> 6, l = q & 63;
    int col = ntg * 16 + (l & 15);
    int k0 = (l >> 4) * 8;
    bf16x8 v;
#pragma unroll
    for (int j = 0; j < 8; ++j) {
      int k = k0 + j;
      float xv = (k < 8) ? mf1_w[ty * 2048 + col * 8 + k]
               : (k == 8) ? mf1_b[ty * 256 + col] : 0.f;
      v[j] = (__bf16)xv;
    }
    ((bf16x8*)(wfdst + 262144))[id] = v;
    return;
  }
  if (b < 190) {
    int id = (b - 136) * 256 + threadIdx.x;  // 13824
    if (id >= 13824) return;
    int tile = id / 384, r = id % 384;
    int kt2 = r / 192, r2 = r % 192, mt2 = r2 >> 6, l = r2 & 63;
    int ebase = tile * 64 + kt2 * 32 + (l >> 4) * 8;
    int n = mt2 * 16 + (l & 15);
    bf16x8 v;
#pragma unroll
    for (int j = 0; j < 8; ++j) {
      int e = ebase + j;
      v[j] = (__bf16)((e < Ee) ? rel_rec[(size_t)e * Nn + n] : 0.f);
    }
    ((bf16x8*)rra)[id] = v;
    return;
  }
  int id = (b - 190) * 256 + threadIdx.x;
  float* T1 = tn;
  float* T2 = T1 + 67600;
  float* To1 = T2 + 67600;
  float* To2 = To1 + 66560;
  float* To3 = To2 + 65536;
  if (id < 67600) { int o = id % 260, k = id / 260; T1[k * 260 + o] = at5_w1[o * 260 + k]; return; }
  id -= 67600;
  if (id < 67600) { int o = id % 260, k = id / 260; T2[k * 260 + o] = at5_w2[o * 260 + k]; return; }
  id -= 67600;
  if (id < 66560) { int o = id & 255, k = id >> 8; To1[k * 256 + o] = o1_w[o * 260 + k]; return; }
  id -= 66560;
  if (id < 65536) { int o = id & 255, k = id >> 8; To2[k * 256 + o] = o2_w[o * 256 + k]; return; }
  id -= 65536;
  if (id < 1024) { int f = id & 3, k = id >> 2; To3[k * 4 + f] = o3_w[f * 256 + k]; }
}

// pm precompute with LDS-staged rel (coalesced).
__global__ __launch_bounds__(256)
void prep_pm(const float* __restrict__ rel_rec, const float* __restrict__ rel_send,
             const float* __restrict__ x, __bf16* __restrict__ pmout) {
  __shared__ float rs[128 * 48], rr[128 * 48], xsl[192];
  const int b = blockIdx.x;               // 1152
  const int slice = b / 18, seg = b % 18;
  const int e0 = seg * 128;
  const int nv = (Ee - e0 < 128) ? (Ee - e0) : 128;
  const int cnt = nv * 48;
  for (int t = threadIdx.x; t < cnt; t += 256) {
    rs[t] = rel_send[(size_t)e0 * 48 + t];
    rr[t] = rel_rec[(size_t)e0 * 48 + t];
  }
  if (threadIdx.x < 192) xsl[threadIdx.x] = x[slice * 192 + threadIdx.x];
  __syncthreads();
  const int el = threadIdx.x & 127, half = threadIdx.x >> 7;
  float a0 = 0.f, a1 = 0.f, a2 = 0.f, a3 = 0.f;
  if (el < nv) {
    const float* rel = half ? rr : rs;
    for (int n = 0; n < 48; ++n) {
      float v = rel[el * 48 + n];
      a0 = fmaf(v, xsl[n * 4 + 0], a0);
      a1 = fmaf(v, xsl[n * 4 + 1], a1);
      a2 = fmaf(v, xsl[n * 4 + 2], a2);
      a3 = fmaf(v, xsl[n * 4 + 3], a3);
    }
  }
  bf16x4 o;
  o[0] = (__bf16)a0; o[1] = (__bf16)a1; o[2] = (__bf16)a2; o[3] = (__bf16)a3;
  *(bf16x4*)(pmout + ((size_t)slice * 2304 + e0 + el) * 8 + half * 4) = o;
}

// 512 blocks x 6 node-rows; 512 threads: K-split across 2 half-K groups (kh)
// doubles wave count (latency-bound kernel); partials combined via pbuf LDS.
template<int MODE>
__global__ __launch_bounds__(512)
void node_kernel(const float* __restrict__ g_agg, const __bf16* __restrict__ partb,
                 const float* __restrict__ x,
                 const float* __restrict__ T1, const float* __restrict__ T2,
                 const float* __restrict__ To1, const float* __restrict__ To2,
                 const float* __restrict__ To3, const float* __restrict__ at5_b1,
                 const float* __restrict__ at5_b2, const float* __restrict__ at5_g,
                 const float* __restrict__ at5_be, const float* __restrict__ o1_b,
                 const float* __restrict__ o2_b, const float* __restrict__ o3_b,
                 float* __restrict__ out) {
  __shared__ __align__(16) float bufA[6 * 264], bufB[6 * 264], pbuf[6 * 264];
  __shared__ float xres[6 * 4];
  const int tid = threadIdx.x;
  const int slice = blockIdx.x >> 3, rg = blockIdx.x & 7;
  const int n0 = rg * 6;
  for (int t = tid; t < 6 * 256; t += 512) {
    int r = t >> 8, h = t & 255;
    float s;
    if (MODE == 1) {
      s = 0.f;
#pragma unroll
      for (int sp = 0; sp < 4; ++sp)
        s += (float)partb[((((size_t)slice * 4 + sp) * Nn) + n0 + r) * Hh + h];
    } else {
      s = g_agg[(size_t)slice * 12288 + (size_t)(n0 + r) * 256 + h];
    }
    bufA[r * 264 + h] = s;
  }
  if (tid < 24) {
    int r = tid >> 2, f = tid & 3;
    float v = x[(size_t)slice * 192 + (n0 + r) * 4 + f];
    bufA[r * 264 + 256 + f] = v;
    xres[tid] = v;
  }
  __syncthreads();

  const int kh = tid >> 8, o0 = tid & 255;

  auto layer = [&](const float* WT, const float* bsrc, const float* in, float* outb,
                   int K, int O, int act, const float* gsc, const float* gbe) {
    const int kmid = (K > 256) ? 132 : 128;
    const int k0 = kh ? kmid : 0;
    const int k1 = kh ? K : kmid;
    const bool x2 = (o0 + 256) < O;   // O==260 overhang (outputs 256..259)
    float a[6] = {0.f, 0.f, 0.f, 0.f, 0.f, 0.f};
    float a2[6] = {0.f, 0.f, 0.f, 0.f, 0.f, 0.f};
    for (int k = k0; k < k1; k += 4) {
      float w0 = WT[k * O + o0], w1 = WT[(k + 1) * O + o0];
      float w2 = WT[(k + 2) * O + o0], w3 = WT[(k + 3) * O + o0];
      float v0 = 0.f, v1 = 0.f, v2 = 0.f, v3 = 0.f;
      if (x2) {
        v0 = WT[k * O + o0 + 256]; v1 = WT[(k + 1) * O + o0 + 256];
        v2 = WT[(k + 2) * O + o0 + 256]; v3 = WT[(k + 3) * O + o0 + 256];
      }
#pragma unroll
      for (int r = 0; r < 6; ++r) {
        f32x4 iv = *(const f32x4*)(in + r * 264 + k);
        a[r] = fmaf(iv[0], w0, a[r]);
        a[r] = fmaf(iv[1], w1, a[r]);
        a[r] = fmaf(iv[2], w2, a[r]);
        a[r] = fmaf(iv[3], w3, a[r]);
        if (x2) {
          a2[r] = fmaf(iv[0], v0, a2[r]);
          a2[r] = fmaf(iv[1], v1, a2[r]);
          a2[r] = fmaf(iv[2], v2, a2[r]);
          a2[r] = fmaf(iv[3], v3, a2[r]);
        }
      }
    }
    if (kh) {
#pragma unroll
      for (int r = 0; r < 6; ++r) pbuf[r * 264 + o0] = a[r];
      if (x2) {
#pragma unroll
        for (int r = 0; r < 6; ++r) pbuf[r * 264 + o0 + 256] = a2[r];
      }
    }
    __syncthreads();
    if (!kh) {
      {
        float bb = bsrc[o0];
        float scv = 1.f, bev = 0.f;
        if (act == 2) { scv = gsc[o0] * BN_RS; bev = gbe[o0]; }
#pragma unroll
        for (int r = 0; r < 6; ++r) {
          float v = a[r] + pbuf[r * 264 + o0] + bb;
          v = (act == 0) ? fmaxf(v, 0.f) : eluf(v);
          if (act == 2) v = v * scv + bev;
          outb[r * 264 + o0] = v;
        }
      }
      if (x2) {
        float bb = bsrc[o0 + 256];
        float scv = 1.f, bev = 0.f;
        if (act == 2) { scv = gsc[o0 + 256] * BN_RS; bev = gbe[o0 + 256]; }
#pragma unroll
        for (int r = 0; r < 6; ++r) {
          float v = a2[r] + pbuf[r * 264 + o0 + 256] + bb;
          v = (act == 0) ? fmaxf(v, 0.f) : eluf(v);
          if (act == 2) v = v * scv + bev;
          outb[r * 264 + o0 + 256] = v;
        }
      }
    }
    __syncthreads();
  };

  layer(T1, at5_b1, bufA, bufB, 260, 260, 1, nullptr, nullptr);
  layer(T2, at5_b2, bufB, bufA, 260, 260, 2, at5_g, at5_be);
  layer(To1, o1_b, bufA, bufB, 260, 256, 0, nullptr, nullptr);
  layer(To2, o2_b, bufB, bufA, 256, 256, 0, nullptr, nullptr);
  if (tid < 24) {
    int r = tid >> 2, f = tid & 3;
    float s = o3_b[f];
    for (int k = 0; k < 256; k += 4) {
      f32x4 iv = *(const f32x4*)(bufA + r * 264 + k);
      s = fmaf(iv[0], To3[k * 4 + f], s);
      s = fmaf(iv[1], To3[(k + 1) * 4 + f], s);
      s = fmaf(iv[2], To3[(k + 2) * 4 + f], s);
      s = fmaf(iv[3], To3[(k + 3) * 4 + f], s);
    }
    out[(size_t)slice * 192 + (n0 + r) * 4 + f] = xres[tid] + s;
  }
}

extern "C" void kernel_launch(void* const* d_in, const int* in_sizes, int n_in,
                              void* d_out, int out_size, void* d_ws, size_t ws_size,
                              hipStream_t stream) {
  const float* x = (const float*)d_in[0];
  const float* rel_rec = (const float*)d_in[1];
  const float* rel_send = (const float*)d_in[2];
  const float* rel_type = (const float*)d_in[3];
  const float* mf1_w = (const float*)d_in[4];
  const float* mf1_b = (const float*)d_in[5];
  const float* mf2_w = (const float*)d_in[6];
  const float* mf2_b = (const float*)d_in[7];
  const float* at1_w1 = (const float*)d_in[8];
  const float* at1_b1 = (const float*)d_in[9];
  const float* at1_w2 = (const float*)d_in[10];
  const float* at1_b2 = (const float*)d_in[11];
  const float* at1_g = (const float*)d_in[12];
  const float* at1_be = (const float*)d_in[13];
  const float* at5_w1 = (const float*)d_in[14];
  const float* at5_b1 = (const float*)d_in[15];
  const float* at5_w2 = (const float*)d_in[16];
  const float* at5_b2 = (const float*)d_in[17];
  const float* at5_g = (const float*)d_in[18];
  const float* at5_be = (const float*)d_in[19];
  const float* o1_w = (const float*)d_in[20];
  const float* o1_b = (const float*)d_in[21];
  const float* o2_w = (const float*)d_in[22];
  const float* o2_b = (const float*)d_in[23];
  const float* o3_w = (const float*)d_in[24];
  const float* o3_b = (const float*)d_in[25];

  char* ws = (char*)d_ws;
  __bf16* wf = (__bf16*)(ws + WS_WF);
  __bf16* rra = (__bf16*)(ws + WS_RRA);
  float* tnode = (float*)(ws + WS_TN);
  float* g_agg = (float*)(ws + WS_AGG);
  __bf16* partb = (__bf16*)(ws + WS_PB);

  const int mode = (ws_size >= WS_NEED1) ? 1 : 0;
  // MODE1: pm lives in the (unused) g_agg slot; MODE0: pm at WS_PB (partb unused)
  __bf16* pm = (mode == 1) ? (__bf16*)(ws + WS_AGG) : (__bf16*)(ws + WS_PB);

  prep_all<<<1239, 256, 0, stream>>>(mf2_w, at1_w1, at1_w2, mf1_w, mf1_b, rel_rec,
                                     at5_w1, at5_w2, o1_w, o2_w, o3_w, wf, rra, tnode);
  prep_pm<<<1152, 256, 0, stream>>>(rel_rec, rel_send, x, pm);

  if (mode == 1) {
    hipFuncSetAttribute((const void*)edge_kernel<1>,
                        hipFuncAttributeMaxDynamicSharedMemorySize, LDS_EDGE_BYTES);
    edge_kernel<1><<<BT * 4, 1024, LDS_EDGE_BYTES, stream>>>(
        rel_type, mf2_b, at1_b1, at1_b2, at1_g, at1_be, wf, rra, pm, g_agg, partb);
    node_kernel<1><<<512, 512, 0, stream>>>(g_agg, partb, x, tnode, tnode + 67600,
                                            tnode + 135200, tnode + 201760, tnode + 267296,
                                            at5_b1, at5_b2, at5_g, at5_be,
                                            o1_b, o2_b, o3_b, (float*)d_out);
  } else {
    hipMemsetAsync(g_agg, 0, (size_t)BT * Nn * Hh * 4, stream);
    hipFuncSetAttribute((const void*)edge_kernel<0>,
                        hipFuncAttributeMaxDynamicSharedMemorySize, LDS_EDGE_BYTES);
    edge_kernel<0><<<BT * 4, 1024, LDS_EDGE_BYTES, stream>>>(
        rel_type, mf2_b, at1_b1, at1_b2, at1_g, at1_be, wf, rra, pm, g_agg, partb);
    node_kernel<0><<<512, 512, 0, stream>>>(g_agg, partb, x, tnode, tnode + 67600,
                                            tnode + 135200, tnode + 201760, tnode + 267296,
                                            at5_b1, at5_b2, at5_g, at5_be,
                                            o1_b, o2_b, o3_b, (float*)d_out);
  }
}